// Round 4
// baseline (1573.857 us; speedup 1.0000x reference)
//
#include <hip/hip_runtime.h>
#include <hip/hip_bf16.h>

typedef __hip_bfloat16 bf16;
typedef __attribute__((ext_vector_type(8))) short short8;
typedef __attribute__((ext_vector_type(4))) float f32x4;

#define NB 16
#define PLANE (256*256)

static __device__ __forceinline__ short f2bf(float v){
    __hip_bfloat16 h = __float2bfloat16(v);
    short s; __builtin_memcpy(&s, &h, 2); return s;
}
static __device__ __forceinline__ float bf2f(short s){
    union { unsigned u; float f; } cv;
    cv.u = ((unsigned)(unsigned short)s) << 16; return cv.f;
}

// agent-scope (cross-XCD coherent, uncached) accesses — bypass per-XCD L2
static __device__ __forceinline__ void  stg_ag(float* p, float v){
    __hip_atomic_store(p, v, __ATOMIC_RELAXED, __HIP_MEMORY_SCOPE_AGENT);
}
static __device__ __forceinline__ float ldg_ag(const float* p){
    return __hip_atomic_load(p, __ATOMIC_RELAXED, __HIP_MEMORY_SCOPE_AGENT);
}
static __device__ __forceinline__ void  stu_ag(unsigned* p, unsigned v){
    __hip_atomic_store(p, v, __ATOMIC_RELAXED, __HIP_MEMORY_SCOPE_AGENT);
}
static __device__ __forceinline__ unsigned ldu_ag(const unsigned* p){
    return __hip_atomic_load(p, __ATOMIC_RELAXED, __HIP_MEMORY_SCOPE_AGENT);
}

// ---------------- first-layer conv 3x3 (small CIN, VALU), output channel-last bf16 ----------------
template<int CIN, int SPLIT, bool RELU>
__global__ __launch_bounds__(256)
void conv3x3_first(const float* __restrict__ in, const float* __restrict__ in2,
                   const float* __restrict__ wgt, const float* __restrict__ bias,
                   bf16* __restrict__ out)
{
    __shared__ float s_in[CIN][18][18];
    __shared__ float s_w[CIN*9*32];
    const int n  = blockIdx.z;
    const int ty0 = blockIdx.y * 16, tx0 = blockIdx.x * 16;
    const int tid = threadIdx.x;

    for (int idx = tid; idx < CIN*9*32; idx += 256) {
        int co = idx & 31; int rest = idx >> 5;     // rest = ci*9 + k
        s_w[idx] = wgt[(co*CIN + rest/9)*9 + rest%9];
    }
    for (int idx = tid; idx < CIN*18*18; idx += 256) {
        int ci = idx / (18*18); int rr = idx % (18*18);
        int yy = rr / 18, xx = rr % 18;
        int y = ty0 + yy - 1, x = tx0 + xx - 1;
        float v = 0.f;
        if (y >= 0 && y < 256 && x >= 0 && x < 256) {
            if (ci < SPLIT) v = in [((size_t)(n*SPLIT + ci)*256 + y)*256 + x];
            else            v = in2[((size_t)(n*(CIN-SPLIT) + (ci-SPLIT))*256 + y)*256 + x];
        }
        s_in[ci][yy][xx] = v;
    }
    __syncthreads();

    const int ty = tid >> 4, tx = tid & 15;
    float acc[32];
    #pragma unroll
    for (int co = 0; co < 32; co++) acc[co] = bias[co];

    #pragma unroll
    for (int ci = 0; ci < CIN; ci++) {
        #pragma unroll
        for (int ky = 0; ky < 3; ky++)
        #pragma unroll
        for (int kx = 0; kx < 3; kx++) {
            float v = s_in[ci][ty+ky][tx+kx];
            const float* wp = &s_w[(ci*9 + ky*3 + kx)*32];
            #pragma unroll
            for (int co = 0; co < 32; co++) acc[co] = fmaf(v, wp[co], acc[co]);
        }
    }
    const int y = ty0 + ty, x = tx0 + tx;
    size_t base = (((size_t)n*256 + y)*256 + x)*32;
    #pragma unroll
    for (int c = 0; c < 32; c += 8) {
        short8 vv;
        #pragma unroll
        for (int j = 0; j < 8; j++) {
            float v = acc[c+j];
            if (RELU) v = fmaxf(v, 0.f);
            vv[j] = f2bf(v);
        }
        *(short8*)((short*)out + base + c) = vv;
    }
}

// ---------------- weight repack for MFMA convs: [co][ci][tap] f32 -> [tap][co][ci] bf16 ----------------
__global__ __launch_bounds__(256)
void wrepack3(const float* __restrict__ a, const float* __restrict__ b,
              const float* __restrict__ c,
              bf16* __restrict__ oa, bf16* __restrict__ ob, bf16* __restrict__ oc)
{
    int j = blockIdx.x*256 + threadIdx.x;        // 0..27647
    if (j >= 3*9216) return;
    int set = j / 9216, r = j % 9216;
    int tap = r >> 10, rem = r & 1023, co = rem >> 5, ci = rem & 31;
    const float* src = (set == 0) ? a : (set == 1) ? b : c;
    bf16* dst = (set == 0) ? oa : (set == 1) ? ob : oc;
    dst[r] = __float2bfloat16(src[(co*32 + ci)*9 + tap]);
}

// ---------------- heavy conv 3x3 (32->32) via MFMA, channel-last bf16 in/out ----------------
template<bool RELU>
__global__ __launch_bounds__(256)
void conv3x3_mfma(const bf16* __restrict__ in, const bf16* __restrict__ wpk,
                  const float* __restrict__ bias, bf16* __restrict__ out)
{
    const int lane = threadIdx.x & 63, wid = threadIdx.x >> 6;
    const int m = lane & 15, quad = lane >> 4, k0 = quad*8;
    const int n  = blockIdx.z;
    const int x0 = blockIdx.x * 16;
    const int y0 = blockIdx.y * 16 + wid * 4;

    const short* wp = (const short*)wpk;
    short8 bw[2][9];
    #pragma unroll
    for (int g = 0; g < 2; g++)
        #pragma unroll
        for (int tap = 0; tap < 9; tap++)
            bw[g][tap] = *(const short8*)(wp + ((tap*32 + g*16 + m)*32 + k0));
    const float b0 = bias[m], b1 = bias[16 + m];

    const short* inp = (const short*)in + (size_t)n*PLANE*32;
    short* outp = (short*)out + (size_t)n*PLANE*32;

    #pragma unroll
    for (int r = 0; r < 4; r++) {
        const int y = y0 + r;
        f32x4 acc0 = { b0, b0, b0, b0 };
        f32x4 acc1 = { b1, b1, b1, b1 };
        #pragma unroll
        for (int ky = 0; ky < 3; ky++) {
            const int yy = y + ky - 1;
            const bool yok = (unsigned)yy < 256u;
            #pragma unroll
            for (int kx = 0; kx < 3; kx++) {
                const int xp = x0 + kx - 1 + m;
                short8 a = { 0,0,0,0,0,0,0,0 };
                if (yok && (unsigned)xp < 256u)
                    a = *(const short8*)(inp + ((size_t)yy*256 + xp)*32 + k0);
                acc0 = __builtin_amdgcn_mfma_f32_16x16x32_bf16(a, bw[0][ky*3+kx], acc0, 0, 0, 0);
                acc1 = __builtin_amdgcn_mfma_f32_16x16x32_bf16(a, bw[1][ky*3+kx], acc1, 0, 0, 0);
            }
        }
        #pragma unroll
        for (int reg = 0; reg < 4; reg++) {
            int px = x0 + quad*4 + reg;
            size_t idx = ((size_t)y*256 + px)*32;
            float v0 = acc0[reg], v1 = acc1[reg];
            if (RELU) { v0 = fmaxf(v0, 0.f); v1 = fmaxf(v1, 0.f); }
            outp[idx + m]      = f2bf(v0);
            outp[idx + 16 + m] = f2bf(v1);
        }
    }
}

// ---------------- final conv 3x3 (32->1), channel-last input ----------------
__global__ __launch_bounds__(256)
void conv3x3_last(const bf16* __restrict__ in, const float* __restrict__ wgt,
                  const float* __restrict__ bias, float* __restrict__ out)
{
    __shared__ float s_w[288];
    int tid = threadIdx.x;
    for (int i = tid; i < 288; i += 256) s_w[i] = wgt[i];
    __syncthreads();
    int gid = blockIdx.x*256 + tid;
    int n = gid >> 16, h = (gid >> 8) & 255, w = gid & 255;
    const short* inp = (const short*)in + (size_t)n*PLANE*32;
    float sum = bias[0];
    #pragma unroll
    for (int ky = 0; ky < 3; ky++) {
        int yy = h + ky - 1;
        if ((unsigned)yy >= 256u) continue;
        #pragma unroll
        for (int kx = 0; kx < 3; kx++) {
            int xx = w + kx - 1;
            if ((unsigned)xx >= 256u) continue;
            const short8* pp = (const short8*)(inp + ((size_t)yy*256 + xx)*32);
            int tap = ky*3 + kx;
            #pragma unroll
            for (int c4 = 0; c4 < 4; c4++) {
                short8 v = pp[c4];
                #pragma unroll
                for (int j = 0; j < 8; j++)
                    sum = fmaf(bf2f(v[j]), s_w[(c4*8+j)*9 + tap], sum);
            }
        }
    }
    out[gid] = sum;
}

// ---------------- squared neighbor diffs over 32 channels, channel-last ----------------
template<bool ACCUM>
__global__ __launch_bounds__(256)
void dvdh_cl(const bf16* __restrict__ f, float* __restrict__ dv, float* __restrict__ dh)
{
    int bid = blockIdx.x;
    int n = bid >> 8, i = bid & 255, j = threadIdx.x;
    const short8* pc = (const short8*)((const short*)f + (((size_t)n*256 + i)*256 + j)*32);
    const short8* pr = (j < 255) ? pc + 4    : pc;
    const short8* pd = (i < 255) ? pc + 1024 : pc;
    float adv = 0.f, adh = 0.f;
    #pragma unroll
    for (int c4 = 0; c4 < 4; c4++) {
        short8 sc = pc[c4], sr = pr[c4], sd = pd[c4];
        #pragma unroll
        for (int e = 0; e < 8; e++) {
            float fc = bf2f(sc[e]);
            float d1 = bf2f(sr[e]) - fc;
            float d2 = bf2f(sd[e]) - fc;
            adh = fmaf(d1, d1, adh);
            adv = fmaf(d2, d2, adv);
        }
    }
    int o = (n*256 + i)*256 + j;
    if (ACCUM) { dv[o] += adv; dh[o] += adh; }
    else       { dv[o]  = adv; dh[o]  = adh; }
}

// ---------------- affinity: packed bf16 (wv,wh) for CG + 5-plane fp32 output ----------------
__global__ __launch_bounds__(256)
void aff2_kernel(const float* __restrict__ dv, const float* __restrict__ dh,
                 const float* __restrict__ llam, const float* __restrict__ lmu,
                 unsigned* __restrict__ wvh, float* __restrict__ aff)
{
    int bid = blockIdx.x;
    int n = bid >> 8, h = bid & 255, w = threadIdx.x;
    float mu = expf(lmu[0]), lam = expf(llam[0]);
    int rb = (n*256 + h)*256 + w;
    float wvv = (h < 255) ? expf(-mu * dv[rb]) : 0.f;
    float whv = (w < 255) ? expf(-mu * dh[rb]) : 0.f;
    unsigned pv = (unsigned)(unsigned short)f2bf(wvv);
    unsigned ph = (unsigned)(unsigned short)f2bf(whv);
    wvh[rb] = pv | (ph << 16);
    float w_up = (h > 0) ? expf(-mu * dv[rb - 256]) : 0.f;
    float w_lf = (w > 0) ? expf(-mu * dh[rb - 1])   : 0.f;
    float ctr  = w_up + wvv + w_lf + whv + lam;
    float* a = aff + ((size_t)n*5)*PLANE + h*256 + w;
    a[0]        = w_up;
    a[PLANE]    = wvv;
    a[2*PLANE]  = w_lf;
    a[3*PLANE]  = whv;
    a[4*PLANE]  = ctr;
}

// ============ persistent CG: 513 blocks = 1 dedicated reducer + 512 workers ============
// Workers: 16 img x 32 tiles of 64x32, 256 thr; x,r,p,Ap in registers (8 px/thread).
// Halo p reconstructed locally from the CG recurrence using the neighbor's published
// border Ap (bit-exact), read from COMPACT per-block edge arrays (192 floats/block,
// double-buffered by phase parity). arrive[b]=seq doubles as the per-neighbor
// edge-ready flag, so halo loads overlap the global-scalar wait. Block 0 only
// gathers: polls 512 flags, reduces 3 dots, publishes results replicated into 8
// per-group 64B lines (gen word last). Zero atomic RMWs anywhere.
// __launch_bounds__(256,4) caps VGPR<=128 -> >=4 blocks/CU -> all 513 co-resident.
__global__ __launch_bounds__(256, 4)
void cg_persist(const unsigned* __restrict__ wvh, const float* __restrict__ mask,
                const float* __restrict__ src, const float* __restrict__ ybic,
                const float* __restrict__ llam, float* __restrict__ xout,
                float* __restrict__ ebuf0, float* __restrict__ ebuf1,
                float* __restrict__ part, unsigned* __restrict__ arrive,
                float* __restrict__ res)
{
    __shared__ float s_pn[66][34];
    __shared__ float s_part[256], s_bs[32];
    __shared__ float s_w3[12], s_out[3];

    const int tid = threadIdx.x;

    // ================= dedicated reducer =================
    if (blockIdx.x == 0) {
        const unsigned i0 = 2*tid, i1 = 2*tid + 1;
        for (unsigned seq = 2; seq <= 101; seq++) {
            while (ldu_ag(&arrive[i0]) < seq) __builtin_amdgcn_s_sleep(2);
            while (ldu_ag(&arrive[i1]) < seq) __builtin_amdgcn_s_sleep(2);
            float pa = ldg_ag(&part[i0])      + ldg_ag(&part[i1]);
            float pb = ldg_ag(&part[512+i0])  + ldg_ag(&part[512+i1]);
            float pc = ldg_ag(&part[1024+i0]) + ldg_ag(&part[1024+i1]);
            #pragma unroll
            for (int o = 32; o > 0; o >>= 1) {
                pa += __shfl_down(pa, o, 64);
                pb += __shfl_down(pb, o, 64);
                pc += __shfl_down(pc, o, 64);
            }
            __syncthreads();
            if ((tid & 63) == 0) { int wv = tid >> 6; s_w3[wv*3]=pa; s_w3[wv*3+1]=pb; s_w3[wv*3+2]=pc; }
            __syncthreads();
            if (tid < 8) {
                float fa = s_w3[0]+s_w3[3]+s_w3[6]+s_w3[9];
                float fb = s_w3[1]+s_w3[4]+s_w3[7]+s_w3[10];
                float fc = s_w3[2]+s_w3[5]+s_w3[8]+s_w3[11];
                float* rl = res + (size_t)tid*16;           // one 64B line per group
                stg_ag(rl+0, fa); stg_ag(rl+1, fb); stg_ag(rl+2, fc);
                asm volatile("s_waitcnt vmcnt(0)" ::: "memory");
                stu_ag((unsigned*)(rl+3), seq);
            }
            __syncthreads();   // protect s_w3 WAR for next round
        }
        return;
    }

    // ================= workers =================
    const int wb = blockIdx.x - 1;
    const int n = wb >> 5, t = wb & 31;
    const int grp = wb & 7;
    const int tyo = (t >> 3) * 64, txo = (t & 7) * 32;
    const int tx = tid & 31, tyb = tid >> 5;
    const int w = txo + tx;
    const float lam = expf(llam[0]);

    const unsigned* wn = wvh + (size_t)n*PLANE;
    const float* ybn = ybic + (size_t)n*PLANE;

    // per-thread stencil constants
    int idx[8];
    unsigned wc[8], wu[8], wl[8];
    float c1[8], rhs[8];
    #pragma unroll
    for (int i = 0; i < 8; i++) {
        int hhi = tyo + tyb + 8*i;
        idx[i] = hhi*256 + w;
        wc[i] = wn[idx[i]];
        wu[i] = (hhi > 0) ? wn[idx[i]-256] : 0u;
        wl[i] = (w > 0)   ? wn[idx[i]-1]   : 0u;
        int bi = n*1024 + (hhi>>3)*32 + (w>>3);
        float mv = mask[bi];
        c1[i]  = lam*mv*(1.f/4096.f);
        rhs[i] = lam*mv*src[bi]*(1.f/64.f);
    }

    // halo-cell ownership: tid<192 owns one cell of the 1-px ring (no corners).
    // nb = neighbor block id whose compact edge array holds this cell; eoff = slot.
    // edge array layout per block: [0,32)=top row, [32,64)=bottom row,
    //                              [64,128)=left col, [128,192)=right col
    const bool hthr = (tid < 192);
    int hy = 0, hx = 0; bool hin = false; int nb = 0, eoff = 0;
    if (hthr) {
        if      (tid < 32)  { hy = tyo - 1;         hx = txo + tid;
                              nb = wb - 8; eoff = 32 + tid; }            // up <- above's bottom
        else if (tid < 64)  { hy = tyo + 64;        hx = txo + (tid-32);
                              nb = wb + 8; eoff = tid - 32; }            // down <- below's top
        else if (tid < 128) { hy = tyo + (tid-64);  hx = txo - 1;
                              nb = wb - 1; eoff = 128 + (tid-64); }      // left <- left's right col
        else                { hy = tyo + (tid-128); hx = txo + 32;
                              nb = wb + 1; eoff = 64 + (tid-128); }      // right <- right's left col
        hin = (hy >= 0 && hy < 256 && hx >= 0 && hx < 256);
    }
    const int hsy = hy - tyo + 1, hsx = hx - txo + 1;

    // avgpool(8x8) of the LDS tile -> s_bs[32]
    #define POOL_BLOCK() do { \
        __syncthreads(); \
        { int segrow_ = tid >> 2, segcol_ = tid & 3; \
          const float* rw_ = &s_pn[1 + segrow_][1 + segcol_*8]; \
          s_part[tid] = rw_[0]+rw_[1]+rw_[2]+rw_[3]+rw_[4]+rw_[5]+rw_[6]+rw_[7]; } \
        __syncthreads(); \
        if (tid < 32) { int brow_ = tid >> 2, bcol_ = tid & 3; float s_ = 0.f; \
          _Pragma("unroll") \
          for (int rr_ = 0; rr_ < 8; rr_++) s_ += s_part[(brow_*8 + rr_)*4 + bcol_]; \
          s_bs[tid] = s_; } \
        __syncthreads(); \
    } while (0)

    // publish tile-border values of arr[] to compact edge array (agent-scope)
    #define PUBLISH_E(arr, ebase) do { \
        float* eb_ = (ebase) + (size_t)wb*192; \
        if (tyb == 0) stg_ag(eb_ + tx, arr[0]); \
        if (tyb == 7) stg_ag(eb_ + 32 + tx, arr[7]); \
        if (tx == 0) { _Pragma("unroll") \
            for (int i_ = 0; i_ < 8; i_++) stg_ag(eb_ + 64 + tyb + 8*i_, arr[i_]); } \
        if (tx == 31){ _Pragma("unroll") \
            for (int i_ = 0; i_ < 8; i_++) stg_ag(eb_ + 128 + tyb + 8*i_, arr[i_]); } \
    } while (0)

    auto matvec = [&](int i) -> float {
        int yy = 1 + tyb + 8*i, xx = 1 + tx;
        float wvd = bf2f((short)(wc[i] & 0xffff));
        float whr = bf2f((short)(wc[i] >> 16));
        float wvu = bf2f((short)(wu[i] & 0xffff));
        float whl = bf2f((short)(wl[i] >> 16));
        float s = wvu*s_pn[yy-1][xx] + wvd*s_pn[yy+1][xx]
                + whl*s_pn[yy][xx-1] + whr*s_pn[yy][xx+1];
        float deg = wvu+wvd+whl+whr;
        return deg*s_pn[yy][xx] - s + c1[i]*s_bs[i*4 + (tx>>3)];
    };

    // block 3-dot reduce -> publish partials + arrival flag (edge stores drained first)
    auto red_arrive = [&](unsigned seq, float va, float vb, float vc){
        #pragma unroll
        for (int o = 32; o > 0; o >>= 1) {
            va += __shfl_down(va, o, 64);
            vb += __shfl_down(vb, o, 64);
            vc += __shfl_down(vc, o, 64);
        }
        asm volatile("s_waitcnt vmcnt(0)" ::: "memory");  // per-wave: drain edge stores
        __syncthreads();
        if ((tid & 63) == 0) { int wv = tid >> 6; s_w3[wv*3]=va; s_w3[wv*3+1]=vb; s_w3[wv*3+2]=vc; }
        __syncthreads();
        if (tid == 0) {
            float pa = s_w3[0]+s_w3[3]+s_w3[6]+s_w3[9];
            float pb = s_w3[1]+s_w3[4]+s_w3[7]+s_w3[10];
            float pc = s_w3[2]+s_w3[5]+s_w3[8]+s_w3[11];
            stg_ag(&part[wb], pa);
            stg_ag(&part[512+wb], pb);
            stg_ag(&part[1024+wb], pc);
            asm volatile("s_waitcnt vmcnt(0)" ::: "memory");
            stu_ag(&arrive[wb], seq);
        }
    };

    // leader waits grid result of phase seq, broadcasts 3 scalars via LDS
    auto gen_wait = [&](unsigned seq){
        if (tid == 0) {
            const float* rl = res + (size_t)grp*16;
            while (ldu_ag((const unsigned*)(rl+3)) < seq) __builtin_amdgcn_s_sleep(2);
            s_out[0] = ldg_ag(rl+0);
            s_out[1] = ldg_ag(rl+1);
            s_out[2] = ldg_ag(rl+2);
        }
        __syncthreads();
    };

    float xv[8], rv[8], pv[8], apv[8];
    float rh = 0.f, phh = 0.f;

    // ---------- phase 1: x0 = ybic, r0 = p0 = b - A x0 (halo via direct global reads);
    //            publish r0 edges -> ebuf1; arrive=1; keep per-thread g0 partial ----------
    #pragma unroll
    for (int i = 0; i < 8; i++) {
        xv[i] = ybn[idx[i]];
        s_pn[1 + tyb + 8*i][1 + tx] = xv[i];
    }
    if (hthr) s_pn[hsy][hsx] = hin ? ybn[hy*256 + hx] : 0.f;
    POOL_BLOCK();
    float g0t = 0.f;
    #pragma unroll
    for (int i = 0; i < 8; i++) {
        float ax = matvec(i);
        float r0 = rhs[i] - ax;
        rv[i] = r0; pv[i] = r0;
        g0t += r0*r0;
    }
    PUBLISH_E(pv, ebuf1);
    asm volatile("s_waitcnt vmcnt(0)" ::: "memory");  // per-wave edge-store drain
    __syncthreads();
    if (tid == 0) stu_ag(&arrive[wb], 1u);

    // ---------- phase 2 (k=0): halo r0 from neighbor edges; Ap0 = A p0;
    //            reduce (g0, pAp0, ApAp0); publish Ap0 edges -> ebuf0; arrive=2 ----------
    {
        float hv = 0.f;
        if (hthr && hin) {
            while (ldu_ag(&arrive[nb]) < 1u) __builtin_amdgcn_s_sleep(2);
            hv = ldg_ag(ebuf1 + (size_t)nb*192 + eoff);
        }
        if (hthr) { rh = hv; phh = hv; s_pn[hsy][hsx] = phh; }
        #pragma unroll
        for (int i = 0; i < 8; i++) s_pn[1 + tyb + 8*i][1 + tx] = pv[i];
        POOL_BLOCK();
        float pap = 0.f, apap = 0.f;
        #pragma unroll
        for (int i = 0; i < 8; i++) {
            float ap = matvec(i);
            apv[i] = ap;
            pap  += pv[i]*ap;
            apap += ap*ap;
        }
        PUBLISH_E(apv, ebuf0);
        red_arrive(2u, g0t, pap, apap);
    }

    // ---------- main loop k=1..99 (phase seq = k+2) ----------
    for (int k = 1; k <= 99; k++) {
        const unsigned seqPrev = (unsigned)(k + 1);
        float* ebR = ((k+1) & 1) ? ebuf1 : ebuf0;   // neighbor Ap_{k-1} edges
        float* ebW = ((k+2) & 1) ? ebuf1 : ebuf0;   // our Ap_k edges

        // issue halo load early — overlaps the scalar gen wait
        float hv = 0.f;
        if (hthr && hin) {
            while (ldu_ag(&arrive[nb]) < seqPrev) __builtin_amdgcn_s_sleep(2);
            hv = ldg_ag(ebR + (size_t)nb*192 + eoff);
        }
        gen_wait(seqPrev);   // -> (g_{k-1}, pAp_{k-1}, ApAp_{k-1})
        float gR = s_out[0], pApR = s_out[1], ApApR = s_out[2];
        float alpha = gR / pApR;
        float beta  = (alpha*alpha*ApApR - gR) / gR;

        if (hthr) {
            rh  = fmaf(-alpha, hv, rh);
            phh = fmaf(beta, phh, rh);
            s_pn[hsy][hsx] = phh;
        }
        float gsum = 0.f;
        #pragma unroll
        for (int i = 0; i < 8; i++) {
            float rN = fmaf(-alpha, apv[i], rv[i]);
            xv[i] = fmaf(alpha, pv[i], xv[i]);
            float pN = fmaf(beta, pv[i], rN);
            rv[i] = rN; pv[i] = pN;
            gsum += rN*rN;
            s_pn[1 + tyb + 8*i][1 + tx] = pN;
        }
        POOL_BLOCK();
        float pap = 0.f, apap = 0.f;
        #pragma unroll
        for (int i = 0; i < 8; i++) {
            float ap = matvec(i);
            apv[i] = ap;
            pap  += pv[i]*ap;
            apap += ap*ap;
        }
        PUBLISH_E(apv, ebW);
        red_arrive((unsigned)(k + 2), gsum, pap, apap);
    }

    // ---------- tail: x += alpha_100 * p_99 ----------
    gen_wait(101u);   // -> (g_99, pAp_99, ApAp_99)
    float alphaT = s_out[0] / s_out[1];
    float* xn = xout + (size_t)n*PLANE;
    #pragma unroll
    for (int i = 0; i < 8; i++) xn[idx[i]] = fmaf(alphaT, pv[i], xv[i]);

    #undef POOL_BLOCK
    #undef PUBLISH_E
}

// ---------------- host ----------------
extern "C" void kernel_launch(void* const* d_in, const int* in_sizes, int n_in,
                              void* d_out, int out_size, void* d_ws, size_t ws_size,
                              hipStream_t stream)
{
    (void)in_sizes; (void)n_in; (void)out_size; (void)ws_size;
    const float* guide = (const float*)d_in[0];
    const float* source= (const float*)d_in[1];
    const float* mask  = (const float*)d_in[2];
    const float* ybic  = (const float*)d_in[3];
    const float* gw1 = (const float*)d_in[4];  const float* gb1 = (const float*)d_in[5];
    const float* gw2 = (const float*)d_in[6];  const float* gb2 = (const float*)d_in[7];
    const float* sw1 = (const float*)d_in[8];  const float* sb1 = (const float*)d_in[9];
    const float* sw2 = (const float*)d_in[10]; const float* sb2 = (const float*)d_in[11];
    const float* vw1 = (const float*)d_in[12]; const float* vb1 = (const float*)d_in[13];
    const float* vw2 = (const float*)d_in[14]; const float* vb2 = (const float*)d_in[15];
    const float* vw3 = (const float*)d_in[16]; const float* vb3 = (const float*)d_in[17];
    const float* llam = (const float*)d_in[18];
    const float* lmu  = (const float*)d_in[19];

    float* out     = (float*)d_out;
    float* x_out   = out;                 // y_pred (16,1,256,256)
    float* var_out = out + 1048576;       // var
    float* aff_out = out + 2097152;       // aff (16,5,256,256)

    // ---- workspace layout ----
    char* ws = (char*)d_ws;
    float*    res   = (float*)ws;                       // 8 x 64B result lines [0,512)
    float*    part  = (float*)(ws + 2048);              // 3*512 floats -> [2048, 8192)
    unsigned* arrive= (unsigned*)(ws + 8192);           // 512 uints -> [8192, 10240)
    bf16*     wpk1  = (bf16*)(ws + 10240);              // 18 KiB each
    bf16*     wpk2  = (bf16*)(ws + 28672);
    bf16*     wpk3  = (bf16*)(ws + 47104);              // ends at 65536
    unsigned* wvh   = (unsigned*)(ws + 65536);          // [64 KiB, 64 KiB + 4 MiB)
    char*     A     = ws + 65536 + (size_t)NB*PLANE*4;  // shared region
    // conv-phase mapping of A:
    bf16*  tmp1 = (bf16*)(A);                                  // 64 MiB
    bf16*  tmp2 = (bf16*)(A + (size_t)NB*32*PLANE*2);          // 64 MiB
    float* dv   = (float*)(A + (size_t)NB*32*PLANE*4);         // 4 MiB
    float* dh   = (float*)(A + (size_t)NB*32*PLANE*4 + (size_t)NB*PLANE*4);
    // CG-phase mapping of A (conv temporaries dead by then): compact edge buffers
    float* ebuf0 = (float*)A;                                  // 512*192 floats
    float* ebuf1 = (float*)(A + (size_t)512*192*4);

    dim3 cgrid(16, 16, NB);

    // zero control region: res [0,512) (within first 2KB) + arrive flags
    hipMemsetAsync(ws, 0, 2048, stream);
    hipMemsetAsync(arrive, 0, 2048, stream);

    // repack the three 32->32 conv weights into MFMA fragment layout
    wrepack3<<<108,256,0,stream>>>(gw2, sw2, vw2, wpk1, wpk2, wpk3);

    // feature branch g = conv(relu(conv(guide)))
    conv3x3_first<3,3,true><<<cgrid,256,0,stream>>>(guide, guide, gw1, gb1, tmp1);
    conv3x3_mfma<false><<<cgrid,256,0,stream>>>(tmp1, wpk1, gb2, tmp2);
    dvdh_cl<false><<<4096,256,0,stream>>>(tmp2, dv, dh);
    // feature branch s = conv(relu(conv(y_bicubic)))
    conv3x3_first<1,1,true><<<cgrid,256,0,stream>>>(ybic, ybic, sw1, sb1, tmp1);
    conv3x3_mfma<false><<<cgrid,256,0,stream>>>(tmp1, wpk2, sb2, tmp2);
    dvdh_cl<true><<<4096,256,0,stream>>>(tmp2, dv, dh);
    aff2_kernel<<<4096,256,0,stream>>>(dv, dh, llam, lmu, wvh, aff_out);
    // variance branch
    conv3x3_first<4,3,true><<<cgrid,256,0,stream>>>(guide, ybic, vw1, vb1, tmp1);
    conv3x3_mfma<true><<<cgrid,256,0,stream>>>(tmp1, wpk3, vb2, tmp2);
    conv3x3_last<<<4096,256,0,stream>>>(tmp2, vw3, vb3, var_out);

    // CG: ONE persistent dispatch — 1 reducer block + 512 workers
    cg_persist<<<513,256,0,stream>>>(wvh, mask, source, ybic, llam, x_out,
                                     ebuf0, ebuf1, part, arrive, res);
}

// Round 5
// 1471.967 us; speedup vs baseline: 1.0692x; 1.0692x over previous
//
#include <hip/hip_runtime.h>
#include <hip/hip_bf16.h>

typedef __hip_bfloat16 bf16;
typedef __attribute__((ext_vector_type(8))) short short8;
typedef __attribute__((ext_vector_type(4))) float f32x4;

#define NB 16
#define PLANE (256*256)

static __device__ __forceinline__ short f2bf(float v){
    __hip_bfloat16 h = __float2bfloat16(v);
    short s; __builtin_memcpy(&s, &h, 2); return s;
}
static __device__ __forceinline__ float bf2f(short s){
    union { unsigned u; float f; } cv;
    cv.u = ((unsigned)(unsigned short)s) << 16; return cv.f;
}

// agent-scope (cross-XCD coherent, uncached) accesses — bypass per-XCD L2
static __device__ __forceinline__ void  stg_ag(float* p, float v){
    __hip_atomic_store(p, v, __ATOMIC_RELAXED, __HIP_MEMORY_SCOPE_AGENT);
}
static __device__ __forceinline__ float ldg_ag(const float* p){
    return __hip_atomic_load(p, __ATOMIC_RELAXED, __HIP_MEMORY_SCOPE_AGENT);
}
static __device__ __forceinline__ void  stu_ag(unsigned* p, unsigned v){
    __hip_atomic_store(p, v, __ATOMIC_RELAXED, __HIP_MEMORY_SCOPE_AGENT);
}
static __device__ __forceinline__ unsigned ldu_ag(const unsigned* p){
    return __hip_atomic_load(p, __ATOMIC_RELAXED, __HIP_MEMORY_SCOPE_AGENT);
}

// ---------------- first-layer conv 3x3 (small CIN, VALU), output channel-last bf16 ----------------
template<int CIN, int SPLIT, bool RELU>
__global__ __launch_bounds__(256)
void conv3x3_first(const float* __restrict__ in, const float* __restrict__ in2,
                   const float* __restrict__ wgt, const float* __restrict__ bias,
                   bf16* __restrict__ out)
{
    __shared__ float s_in[CIN][18][18];
    __shared__ float s_w[CIN*9*32];
    const int n  = blockIdx.z;
    const int ty0 = blockIdx.y * 16, tx0 = blockIdx.x * 16;
    const int tid = threadIdx.x;

    for (int idx = tid; idx < CIN*9*32; idx += 256) {
        int co = idx & 31; int rest = idx >> 5;     // rest = ci*9 + k
        s_w[idx] = wgt[(co*CIN + rest/9)*9 + rest%9];
    }
    for (int idx = tid; idx < CIN*18*18; idx += 256) {
        int ci = idx / (18*18); int rr = idx % (18*18);
        int yy = rr / 18, xx = rr % 18;
        int y = ty0 + yy - 1, x = tx0 + xx - 1;
        float v = 0.f;
        if (y >= 0 && y < 256 && x >= 0 && x < 256) {
            if (ci < SPLIT) v = in [((size_t)(n*SPLIT + ci)*256 + y)*256 + x];
            else            v = in2[((size_t)(n*(CIN-SPLIT) + (ci-SPLIT))*256 + y)*256 + x];
        }
        s_in[ci][yy][xx] = v;
    }
    __syncthreads();

    const int ty = tid >> 4, tx = tid & 15;
    float acc[32];
    #pragma unroll
    for (int co = 0; co < 32; co++) acc[co] = bias[co];

    #pragma unroll
    for (int ci = 0; ci < CIN; ci++) {
        #pragma unroll
        for (int ky = 0; ky < 3; ky++)
        #pragma unroll
        for (int kx = 0; kx < 3; kx++) {
            float v = s_in[ci][ty+ky][tx+kx];
            const float* wp = &s_w[(ci*9 + ky*3 + kx)*32];
            #pragma unroll
            for (int co = 0; co < 32; co++) acc[co] = fmaf(v, wp[co], acc[co]);
        }
    }
    const int y = ty0 + ty, x = tx0 + tx;
    size_t base = (((size_t)n*256 + y)*256 + x)*32;
    #pragma unroll
    for (int c = 0; c < 32; c += 8) {
        short8 vv;
        #pragma unroll
        for (int j = 0; j < 8; j++) {
            float v = acc[c+j];
            if (RELU) v = fmaxf(v, 0.f);
            vv[j] = f2bf(v);
        }
        *(short8*)((short*)out + base + c) = vv;
    }
}

// ---------------- weight repack for MFMA convs: [co][ci][tap] f32 -> [tap][co][ci] bf16 ----------------
__global__ __launch_bounds__(256)
void wrepack3(const float* __restrict__ a, const float* __restrict__ b,
              const float* __restrict__ c,
              bf16* __restrict__ oa, bf16* __restrict__ ob, bf16* __restrict__ oc)
{
    int j = blockIdx.x*256 + threadIdx.x;        // 0..27647
    if (j >= 3*9216) return;
    int set = j / 9216, r = j % 9216;
    int tap = r >> 10, rem = r & 1023, co = rem >> 5, ci = rem & 31;
    const float* src = (set == 0) ? a : (set == 1) ? b : c;
    bf16* dst = (set == 0) ? oa : (set == 1) ? ob : oc;
    dst[r] = __float2bfloat16(src[(co*32 + ci)*9 + tap]);
}

// ---------------- heavy conv 3x3 (32->32) via MFMA, channel-last bf16 in/out ----------------
template<bool RELU>
__global__ __launch_bounds__(256)
void conv3x3_mfma(const bf16* __restrict__ in, const bf16* __restrict__ wpk,
                  const float* __restrict__ bias, bf16* __restrict__ out)
{
    const int lane = threadIdx.x & 63, wid = threadIdx.x >> 6;
    const int m = lane & 15, quad = lane >> 4, k0 = quad*8;
    const int n  = blockIdx.z;
    const int x0 = blockIdx.x * 16;
    const int y0 = blockIdx.y * 16 + wid * 4;

    const short* wp = (const short*)wpk;
    short8 bw[2][9];
    #pragma unroll
    for (int g = 0; g < 2; g++)
        #pragma unroll
        for (int tap = 0; tap < 9; tap++)
            bw[g][tap] = *(const short8*)(wp + ((tap*32 + g*16 + m)*32 + k0));
    const float b0 = bias[m], b1 = bias[16 + m];

    const short* inp = (const short*)in + (size_t)n*PLANE*32;
    short* outp = (short*)out + (size_t)n*PLANE*32;

    #pragma unroll
    for (int r = 0; r < 4; r++) {
        const int y = y0 + r;
        f32x4 acc0 = { b0, b0, b0, b0 };
        f32x4 acc1 = { b1, b1, b1, b1 };
        #pragma unroll
        for (int ky = 0; ky < 3; ky++) {
            const int yy = y + ky - 1;
            const bool yok = (unsigned)yy < 256u;
            #pragma unroll
            for (int kx = 0; kx < 3; kx++) {
                const int xp = x0 + kx - 1 + m;
                short8 a = { 0,0,0,0,0,0,0,0 };
                if (yok && (unsigned)xp < 256u)
                    a = *(const short8*)(inp + ((size_t)yy*256 + xp)*32 + k0);
                acc0 = __builtin_amdgcn_mfma_f32_16x16x32_bf16(a, bw[0][ky*3+kx], acc0, 0, 0, 0);
                acc1 = __builtin_amdgcn_mfma_f32_16x16x32_bf16(a, bw[1][ky*3+kx], acc1, 0, 0, 0);
            }
        }
        #pragma unroll
        for (int reg = 0; reg < 4; reg++) {
            int px = x0 + quad*4 + reg;
            size_t idx = ((size_t)y*256 + px)*32;
            float v0 = acc0[reg], v1 = acc1[reg];
            if (RELU) { v0 = fmaxf(v0, 0.f); v1 = fmaxf(v1, 0.f); }
            outp[idx + m]      = f2bf(v0);
            outp[idx + 16 + m] = f2bf(v1);
        }
    }
}

// ---------------- final conv 3x3 (32->1), channel-last input ----------------
__global__ __launch_bounds__(256)
void conv3x3_last(const bf16* __restrict__ in, const float* __restrict__ wgt,
                  const float* __restrict__ bias, float* __restrict__ out)
{
    __shared__ float s_w[288];
    int tid = threadIdx.x;
    for (int i = tid; i < 288; i += 256) s_w[i] = wgt[i];
    __syncthreads();
    int gid = blockIdx.x*256 + tid;
    int n = gid >> 16, h = (gid >> 8) & 255, w = gid & 255;
    const short* inp = (const short*)in + (size_t)n*PLANE*32;
    float sum = bias[0];
    #pragma unroll
    for (int ky = 0; ky < 3; ky++) {
        int yy = h + ky - 1;
        if ((unsigned)yy >= 256u) continue;
        #pragma unroll
        for (int kx = 0; kx < 3; kx++) {
            int xx = w + kx - 1;
            if ((unsigned)xx >= 256u) continue;
            const short8* pp = (const short8*)(inp + ((size_t)yy*256 + xx)*32);
            int tap = ky*3 + kx;
            #pragma unroll
            for (int c4 = 0; c4 < 4; c4++) {
                short8 v = pp[c4];
                #pragma unroll
                for (int j = 0; j < 8; j++)
                    sum = fmaf(bf2f(v[j]), s_w[(c4*8+j)*9 + tap], sum);
            }
        }
    }
    out[gid] = sum;
}

// ---------------- squared neighbor diffs over 32 channels, channel-last ----------------
template<bool ACCUM>
__global__ __launch_bounds__(256)
void dvdh_cl(const bf16* __restrict__ f, float* __restrict__ dv, float* __restrict__ dh)
{
    int bid = blockIdx.x;
    int n = bid >> 8, i = bid & 255, j = threadIdx.x;
    const short8* pc = (const short8*)((const short*)f + (((size_t)n*256 + i)*256 + j)*32);
    const short8* pr = (j < 255) ? pc + 4    : pc;
    const short8* pd = (i < 255) ? pc + 1024 : pc;
    float adv = 0.f, adh = 0.f;
    #pragma unroll
    for (int c4 = 0; c4 < 4; c4++) {
        short8 sc = pc[c4], sr = pr[c4], sd = pd[c4];
        #pragma unroll
        for (int e = 0; e < 8; e++) {
            float fc = bf2f(sc[e]);
            float d1 = bf2f(sr[e]) - fc;
            float d2 = bf2f(sd[e]) - fc;
            adh = fmaf(d1, d1, adh);
            adv = fmaf(d2, d2, adv);
        }
    }
    int o = (n*256 + i)*256 + j;
    if (ACCUM) { dv[o] += adv; dh[o] += adh; }
    else       { dv[o]  = adv; dh[o]  = adh; }
}

// ---------------- affinity: packed bf16 (wv,wh) for CG + 5-plane fp32 output ----------------
__global__ __launch_bounds__(256)
void aff2_kernel(const float* __restrict__ dv, const float* __restrict__ dh,
                 const float* __restrict__ llam, const float* __restrict__ lmu,
                 unsigned* __restrict__ wvh, float* __restrict__ aff)
{
    int bid = blockIdx.x;
    int n = bid >> 8, h = bid & 255, w = threadIdx.x;
    float mu = expf(lmu[0]), lam = expf(llam[0]);
    int rb = (n*256 + h)*256 + w;
    float wvv = (h < 255) ? expf(-mu * dv[rb]) : 0.f;
    float whv = (w < 255) ? expf(-mu * dh[rb]) : 0.f;
    unsigned pv = (unsigned)(unsigned short)f2bf(wvv);
    unsigned ph = (unsigned)(unsigned short)f2bf(whv);
    wvh[rb] = pv | (ph << 16);
    float w_up = (h > 0) ? expf(-mu * dv[rb - 256]) : 0.f;
    float w_lf = (w > 0) ? expf(-mu * dh[rb - 1])   : 0.f;
    float ctr  = w_up + wvv + w_lf + whv + lam;
    float* a = aff + ((size_t)n*5)*PLANE + h*256 + w;
    a[0]        = w_up;
    a[PLANE]    = wvv;
    a[2*PLANE]  = w_lf;
    a[3*PLANE]  = whv;
    a[4*PLANE]  = ctr;
}

// ============ persistent CG: 512 worker blocks, replicated all-reduce, no reducer ============
// 16 img x 32 tiles of 64x32, 256 thr, __launch_bounds__(256,2) -> VGPR<=256 (no spill),
// 2 blocks/CU capacity = 512 -> all co-resident. x,r,p,Ap in registers (8 px/thread).
// Per phase: each block publishes compact border-Ap edges + 3 dot-partials + arrive flag
// (monotone seq). EVERY block then polls all 512 flags (2/thread) and redundantly
// tree-reduces the 512x3 partials itself (L3-resident broadcast read, ~6KB) — no
// dedicated reducer, no result round-trip. The all-flag wait IS the barrier, so
// neighbor edges are implicitly ready. part[] double-buffered by seq parity (overwrite
// of parity-p slots requires all flags >= p+1, which proves all parity-p gathers done).
// Zero atomic RMWs. Reduction tree order identical to prior rounds (bit-identical CG).
__global__ __launch_bounds__(256, 2)
void cg_persist(const unsigned* __restrict__ wvh, const float* __restrict__ mask,
                const float* __restrict__ src, const float* __restrict__ ybic,
                const float* __restrict__ llam, float* __restrict__ xout,
                float* __restrict__ ebuf0, float* __restrict__ ebuf1,
                float* __restrict__ part, unsigned* __restrict__ arrive)
{
    __shared__ float s_pn[66][34];
    __shared__ float s_part[256], s_bs[32];
    __shared__ float s_w3[12];

    const int tid = threadIdx.x;
    const int wb = blockIdx.x;
    const int n = wb >> 5, t = wb & 31;
    const int tyo = (t >> 3) * 64, txo = (t & 7) * 32;
    const int tx = tid & 31, tyb = tid >> 5;
    const int w = txo + tx;
    const float lam = expf(llam[0]);
    const unsigned i0 = 2*tid, i1 = 2*tid + 1;

    const unsigned* wn = wvh + (size_t)n*PLANE;
    const float* ybn = ybic + (size_t)n*PLANE;

    // per-thread stencil constants
    int idx[8];
    unsigned wc[8], wu[8], wl[8];
    float c1[8], rhs[8];
    #pragma unroll
    for (int i = 0; i < 8; i++) {
        int hhi = tyo + tyb + 8*i;
        idx[i] = hhi*256 + w;
        wc[i] = wn[idx[i]];
        wu[i] = (hhi > 0) ? wn[idx[i]-256] : 0u;
        wl[i] = (w > 0)   ? wn[idx[i]-1]   : 0u;
        int bi = n*1024 + (hhi>>3)*32 + (w>>3);
        float mv = mask[bi];
        c1[i]  = lam*mv*(1.f/4096.f);
        rhs[i] = lam*mv*src[bi]*(1.f/64.f);
    }

    // halo-cell ownership: tid<192 owns one cell of the 1-px ring (no corners).
    // nb = neighbor block id whose compact edge array holds this cell; eoff = slot.
    // edge array layout per block: [0,32)=top row, [32,64)=bottom row,
    //                              [64,128)=left col, [128,192)=right col
    const bool hthr = (tid < 192);
    int hy = 0, hx = 0; bool hin = false; int nb = 0, eoff = 0;
    if (hthr) {
        if      (tid < 32)  { hy = tyo - 1;         hx = txo + tid;
                              nb = wb - 8; eoff = 32 + tid; }            // up <- above's bottom
        else if (tid < 64)  { hy = tyo + 64;        hx = txo + (tid-32);
                              nb = wb + 8; eoff = tid - 32; }            // down <- below's top
        else if (tid < 128) { hy = tyo + (tid-64);  hx = txo - 1;
                              nb = wb - 1; eoff = 128 + (tid-64); }      // left <- left's right col
        else                { hy = tyo + (tid-128); hx = txo + 32;
                              nb = wb + 1; eoff = 64 + (tid-128); }      // right <- right's left col
        hin = (hy >= 0 && hy < 256 && hx >= 0 && hx < 256);
    }
    const int hsy = hy - tyo + 1, hsx = hx - txo + 1;

    // avgpool(8x8) of the LDS tile -> s_bs[32]
    #define POOL_BLOCK() do { \
        __syncthreads(); \
        { int segrow_ = tid >> 2, segcol_ = tid & 3; \
          const float* rw_ = &s_pn[1 + segrow_][1 + segcol_*8]; \
          s_part[tid] = rw_[0]+rw_[1]+rw_[2]+rw_[3]+rw_[4]+rw_[5]+rw_[6]+rw_[7]; } \
        __syncthreads(); \
        if (tid < 32) { int brow_ = tid >> 2, bcol_ = tid & 3; float s_ = 0.f; \
          _Pragma("unroll") \
          for (int rr_ = 0; rr_ < 8; rr_++) s_ += s_part[(brow_*8 + rr_)*4 + bcol_]; \
          s_bs[tid] = s_; } \
        __syncthreads(); \
    } while (0)

    // publish tile-border values of arr[] to compact edge array (agent-scope)
    #define PUBLISH_E(arr, ebase) do { \
        float* eb_ = (ebase) + (size_t)wb*192; \
        if (tyb == 0) stg_ag(eb_ + tx, arr[0]); \
        if (tyb == 7) stg_ag(eb_ + 32 + tx, arr[7]); \
        if (tx == 0) { _Pragma("unroll") \
            for (int i_ = 0; i_ < 8; i_++) stg_ag(eb_ + 64 + tyb + 8*i_, arr[i_]); } \
        if (tx == 31){ _Pragma("unroll") \
            for (int i_ = 0; i_ < 8; i_++) stg_ag(eb_ + 128 + tyb + 8*i_, arr[i_]); } \
    } while (0)

    auto matvec = [&](int i) -> float {
        int yy = 1 + tyb + 8*i, xx = 1 + tx;
        float wvd = bf2f((short)(wc[i] & 0xffff));
        float whr = bf2f((short)(wc[i] >> 16));
        float wvu = bf2f((short)(wu[i] & 0xffff));
        float whl = bf2f((short)(wl[i] >> 16));
        float s = wvu*s_pn[yy-1][xx] + wvd*s_pn[yy+1][xx]
                + whl*s_pn[yy][xx-1] + whr*s_pn[yy][xx+1];
        float deg = wvu+wvd+whl+whr;
        return deg*s_pn[yy][xx] - s + c1[i]*s_bs[i*4 + (tx>>3)];
    };

    // block 3-dot reduce -> publish partials (parity seq&1) + arrival flag.
    // Each wave drains its own edge stores (vmcnt) before the barrier; leader's
    // part stores drain before the flag store.
    auto publish_red = [&](unsigned seq, float va, float vb, float vc){
        #pragma unroll
        for (int o = 32; o > 0; o >>= 1) {
            va += __shfl_down(va, o, 64);
            vb += __shfl_down(vb, o, 64);
            vc += __shfl_down(vc, o, 64);
        }
        asm volatile("s_waitcnt vmcnt(0)" ::: "memory");  // per-wave edge-store drain
        __syncthreads();
        if ((tid & 63) == 0) { int wv = tid >> 6; s_w3[wv*3]=va; s_w3[wv*3+1]=vb; s_w3[wv*3+2]=vc; }
        __syncthreads();
        if (tid == 0) {
            float* pp = part + (size_t)(seq & 1)*1536;
            stg_ag(pp + wb,        s_w3[0]+s_w3[3]+s_w3[6]+s_w3[9]);
            stg_ag(pp + 512 + wb,  s_w3[1]+s_w3[4]+s_w3[7]+s_w3[10]);
            stg_ag(pp + 1024 + wb, s_w3[2]+s_w3[5]+s_w3[8]+s_w3[11]);
            asm volatile("s_waitcnt vmcnt(0)" ::: "memory");
            stu_ag(&arrive[wb], seq);
        }
    };

    // full barrier + replicated gather of the 3 grid dots (parity seq&1).
    // All threads return identical (o0,o1,o2); tree order fixed -> deterministic.
    float o0, o1, o2;
    auto allred = [&](unsigned seq){
        while (ldu_ag(&arrive[i0]) < seq) __builtin_amdgcn_s_sleep(2);
        while (ldu_ag(&arrive[i1]) < seq) __builtin_amdgcn_s_sleep(2);
        const float* pp = part + (size_t)(seq & 1)*1536;
        float pa = ldg_ag(pp + i0)        + ldg_ag(pp + i1);
        float pb = ldg_ag(pp + 512 + i0)  + ldg_ag(pp + 512 + i1);
        float pc = ldg_ag(pp + 1024 + i0) + ldg_ag(pp + 1024 + i1);
        #pragma unroll
        for (int o = 32; o > 0; o >>= 1) {
            pa += __shfl_down(pa, o, 64);
            pb += __shfl_down(pb, o, 64);
            pc += __shfl_down(pc, o, 64);
        }
        __syncthreads();   // WAR protect s_w3 (prev phase fully consumed)
        if ((tid & 63) == 0) { int wv = tid >> 6; s_w3[wv*3]=pa; s_w3[wv*3+1]=pb; s_w3[wv*3+2]=pc; }
        __syncthreads();   // block-wide: all 512 flags verified >= seq from here on
        o0 = s_w3[0]+s_w3[3]+s_w3[6]+s_w3[9];
        o1 = s_w3[1]+s_w3[4]+s_w3[7]+s_w3[10];
        o2 = s_w3[2]+s_w3[5]+s_w3[8]+s_w3[11];
    };

    float xv[8], rv[8], pv[8], apv[8];
    float rh = 0.f, phh = 0.f;

    // ---------- phase 1: x0 = ybic, r0 = p0 = b - A x0 (halo via direct global reads);
    //            publish r0 edges -> ebuf1; flag=1; keep per-thread g0 partial ----------
    #pragma unroll
    for (int i = 0; i < 8; i++) {
        xv[i] = ybn[idx[i]];
        s_pn[1 + tyb + 8*i][1 + tx] = xv[i];
    }
    if (hthr) s_pn[hsy][hsx] = hin ? ybn[hy*256 + hx] : 0.f;
    POOL_BLOCK();
    float g0t = 0.f;
    #pragma unroll
    for (int i = 0; i < 8; i++) {
        float ax = matvec(i);
        float r0 = rhs[i] - ax;
        rv[i] = r0; pv[i] = r0;
        g0t += r0*r0;
    }
    PUBLISH_E(pv, ebuf1);
    asm volatile("s_waitcnt vmcnt(0)" ::: "memory");
    __syncthreads();
    if (tid == 0) stu_ag(&arrive[wb], 1u);

    // ---------- phase 2 (k=0): flag-barrier(1); halo r0 from neighbor edges;
    //            Ap0 = A p0; publish Ap0 edges -> ebuf0; parts (g0,pAp0,ApAp0) flag=2 ----------
    {
        while (ldu_ag(&arrive[i0]) < 1u) __builtin_amdgcn_s_sleep(2);
        while (ldu_ag(&arrive[i1]) < 1u) __builtin_amdgcn_s_sleep(2);
        __syncthreads();   // all 512 flags >= 1 -> all seq-1 edges visible
        float hv = 0.f;
        if (hthr && hin) hv = ldg_ag(ebuf1 + (size_t)nb*192 + eoff);
        if (hthr) { rh = hv; phh = hv; s_pn[hsy][hsx] = phh; }
        #pragma unroll
        for (int i = 0; i < 8; i++) s_pn[1 + tyb + 8*i][1 + tx] = pv[i];
        POOL_BLOCK();
        float pap = 0.f, apap = 0.f;
        #pragma unroll
        for (int i = 0; i < 8; i++) {
            float ap = matvec(i);
            apv[i] = ap;
            pap  += pv[i]*ap;
            apap += ap*ap;
        }
        PUBLISH_E(apv, ebuf0);
        publish_red(2u, g0t, pap, apap);
    }

    // ---------- main loop k=1..99 (phase seq = k+2; allred(k+1) -> prev scalars) ----------
    for (int k = 1; k <= 99; k++) {
        float* ebR = ((k+1) & 1) ? ebuf1 : ebuf0;   // neighbor Ap_{k-1} edges (seq k+1)
        float* ebW = ((k+2) & 1) ? ebuf1 : ebuf0;   // our Ap_k edges (seq k+2)

        allred((unsigned)(k + 1));                  // -> (g_{k-1}, pAp_{k-1}, ApAp_{k-1})
        float alpha = o0 / o1;
        float beta  = (alpha*alpha*o2 - o0) / o0;

        // halo load overlaps the interior update below (hv used last)
        float hv = 0.f;
        if (hthr && hin) hv = ldg_ag(ebR + (size_t)nb*192 + eoff);

        float gsum = 0.f;
        #pragma unroll
        for (int i = 0; i < 8; i++) {
            float rN = fmaf(-alpha, apv[i], rv[i]);
            xv[i] = fmaf(alpha, pv[i], xv[i]);
            float pN = fmaf(beta, pv[i], rN);
            rv[i] = rN; pv[i] = pN;
            gsum += rN*rN;
            s_pn[1 + tyb + 8*i][1 + tx] = pN;
        }
        if (hthr) {
            rh  = fmaf(-alpha, hv, rh);
            phh = fmaf(beta, phh, rh);
            s_pn[hsy][hsx] = phh;
        }
        POOL_BLOCK();
        float pap = 0.f, apap = 0.f;
        #pragma unroll
        for (int i = 0; i < 8; i++) {
            float ap = matvec(i);
            apv[i] = ap;
            pap  += pv[i]*ap;
            apap += ap*ap;
        }
        PUBLISH_E(apv, ebW);
        publish_red((unsigned)(k + 2), gsum, pap, apap);
    }

    // ---------- tail: x += alpha_100 * p_99 ----------
    allred(101u);   // -> (g_99, pAp_99, ApAp_99)
    float alphaT = o0 / o1;
    float* xn = xout + (size_t)n*PLANE;
    #pragma unroll
    for (int i = 0; i < 8; i++) xn[idx[i]] = fmaf(alphaT, pv[i], xv[i]);

    #undef POOL_BLOCK
    #undef PUBLISH_E
}

// ---------------- host ----------------
extern "C" void kernel_launch(void* const* d_in, const int* in_sizes, int n_in,
                              void* d_out, int out_size, void* d_ws, size_t ws_size,
                              hipStream_t stream)
{
    (void)in_sizes; (void)n_in; (void)out_size; (void)ws_size;
    const float* guide = (const float*)d_in[0];
    const float* source= (const float*)d_in[1];
    const float* mask  = (const float*)d_in[2];
    const float* ybic  = (const float*)d_in[3];
    const float* gw1 = (const float*)d_in[4];  const float* gb1 = (const float*)d_in[5];
    const float* gw2 = (const float*)d_in[6];  const float* gb2 = (const float*)d_in[7];
    const float* sw1 = (const float*)d_in[8];  const float* sb1 = (const float*)d_in[9];
    const float* sw2 = (const float*)d_in[10]; const float* sb2 = (const float*)d_in[11];
    const float* vw1 = (const float*)d_in[12]; const float* vb1 = (const float*)d_in[13];
    const float* vw2 = (const float*)d_in[14]; const float* vb2 = (const float*)d_in[15];
    const float* vw3 = (const float*)d_in[16]; const float* vb3 = (const float*)d_in[17];
    const float* llam = (const float*)d_in[18];
    const float* lmu  = (const float*)d_in[19];

    float* out     = (float*)d_out;
    float* x_out   = out;                 // y_pred (16,1,256,256)
    float* var_out = out + 1048576;       // var
    float* aff_out = out + 2097152;       // aff (16,5,256,256)

    // ---- workspace layout ----
    char* ws = (char*)d_ws;
    float*    part  = (float*)(ws + 2048);              // 2 parity x 1536 floats -> [2048, 14336)
    unsigned* arrive= (unsigned*)(ws + 14336);          // 512 uints -> [14336, 16384)
    bf16*     wpk1  = (bf16*)(ws + 16384);              // 18 KiB each
    bf16*     wpk2  = (bf16*)(ws + 34816);
    bf16*     wpk3  = (bf16*)(ws + 53248);              // ends at 71680
    unsigned* wvh   = (unsigned*)(ws + 131072);         // [128 KiB, 128 KiB + 4 MiB)
    char*     A     = ws + 131072 + (size_t)NB*PLANE*4; // shared region
    // conv-phase mapping of A:
    bf16*  tmp1 = (bf16*)(A);                                  // 64 MiB
    bf16*  tmp2 = (bf16*)(A + (size_t)NB*32*PLANE*2);          // 64 MiB
    float* dv   = (float*)(A + (size_t)NB*32*PLANE*4);         // 4 MiB
    float* dh   = (float*)(A + (size_t)NB*32*PLANE*4 + (size_t)NB*PLANE*4);
    // CG-phase mapping of A (conv temporaries dead by then): compact edge buffers
    float* ebuf0 = (float*)A;                                  // 512*192 floats
    float* ebuf1 = (float*)(A + (size_t)512*192*4);

    dim3 cgrid(16, 16, NB);

    // zero arrive flags (part never read before first write)
    hipMemsetAsync(arrive, 0, 2048, stream);

    // repack the three 32->32 conv weights into MFMA fragment layout
    wrepack3<<<108,256,0,stream>>>(gw2, sw2, vw2, wpk1, wpk2, wpk3);

    // feature branch g = conv(relu(conv(guide)))
    conv3x3_first<3,3,true><<<cgrid,256,0,stream>>>(guide, guide, gw1, gb1, tmp1);
    conv3x3_mfma<false><<<cgrid,256,0,stream>>>(tmp1, wpk1, gb2, tmp2);
    dvdh_cl<false><<<4096,256,0,stream>>>(tmp2, dv, dh);
    // feature branch s = conv(relu(conv(y_bicubic)))
    conv3x3_first<1,1,true><<<cgrid,256,0,stream>>>(ybic, ybic, sw1, sb1, tmp1);
    conv3x3_mfma<false><<<cgrid,256,0,stream>>>(tmp1, wpk2, sb2, tmp2);
    dvdh_cl<true><<<4096,256,0,stream>>>(tmp2, dv, dh);
    aff2_kernel<<<4096,256,0,stream>>>(dv, dh, llam, lmu, wvh, aff_out);
    // variance branch
    conv3x3_first<4,3,true><<<cgrid,256,0,stream>>>(guide, ybic, vw1, vb1, tmp1);
    conv3x3_mfma<true><<<cgrid,256,0,stream>>>(tmp1, wpk3, vb2, tmp2);
    conv3x3_last<<<4096,256,0,stream>>>(tmp2, vw3, vb3, var_out);

    // CG: ONE persistent dispatch — 512 workers, replicated all-reduce barrier
    cg_persist<<<512,256,0,stream>>>(wvh, mask, source, ybic, llam, x_out,
                                     ebuf0, ebuf1, part, arrive);
}

// Round 6
// 1442.641 us; speedup vs baseline: 1.0910x; 1.0203x over previous
//
#include <hip/hip_runtime.h>
#include <hip/hip_bf16.h>

typedef __hip_bfloat16 bf16;
typedef __attribute__((ext_vector_type(8))) short short8;
typedef __attribute__((ext_vector_type(4))) float f32x4;

#define NB 16
#define PLANE (256*256)

static __device__ __forceinline__ short f2bf(float v){
    __hip_bfloat16 h = __float2bfloat16(v);
    short s; __builtin_memcpy(&s, &h, 2); return s;
}
static __device__ __forceinline__ float bf2f(short s){
    union { unsigned u; float f; } cv;
    cv.u = ((unsigned)(unsigned short)s) << 16; return cv.f;
}

// agent-scope (cross-XCD coherent, uncached) accesses — bypass per-XCD L2
static __device__ __forceinline__ void  stg_ag(float* p, float v){
    __hip_atomic_store(p, v, __ATOMIC_RELAXED, __HIP_MEMORY_SCOPE_AGENT);
}
static __device__ __forceinline__ float ldg_ag(const float* p){
    return __hip_atomic_load(p, __ATOMIC_RELAXED, __HIP_MEMORY_SCOPE_AGENT);
}
static __device__ __forceinline__ void  stu_ag(unsigned* p, unsigned v){
    __hip_atomic_store(p, v, __ATOMIC_RELAXED, __HIP_MEMORY_SCOPE_AGENT);
}
static __device__ __forceinline__ unsigned ldu_ag(const unsigned* p){
    return __hip_atomic_load(p, __ATOMIC_RELAXED, __HIP_MEMORY_SCOPE_AGENT);
}

// ---------------- first-layer conv 3x3 (small CIN, VALU), output channel-last bf16 ----------------
template<int CIN, int SPLIT, bool RELU>
__global__ __launch_bounds__(256)
void conv3x3_first(const float* __restrict__ in, const float* __restrict__ in2,
                   const float* __restrict__ wgt, const float* __restrict__ bias,
                   bf16* __restrict__ out)
{
    __shared__ float s_in[CIN][18][18];
    __shared__ float s_w[CIN*9*32];
    const int n  = blockIdx.z;
    const int ty0 = blockIdx.y * 16, tx0 = blockIdx.x * 16;
    const int tid = threadIdx.x;

    for (int idx = tid; idx < CIN*9*32; idx += 256) {
        int co = idx & 31; int rest = idx >> 5;     // rest = ci*9 + k
        s_w[idx] = wgt[(co*CIN + rest/9)*9 + rest%9];
    }
    for (int idx = tid; idx < CIN*18*18; idx += 256) {
        int ci = idx / (18*18); int rr = idx % (18*18);
        int yy = rr / 18, xx = rr % 18;
        int y = ty0 + yy - 1, x = tx0 + xx - 1;
        float v = 0.f;
        if (y >= 0 && y < 256 && x >= 0 && x < 256) {
            if (ci < SPLIT) v = in [((size_t)(n*SPLIT + ci)*256 + y)*256 + x];
            else            v = in2[((size_t)(n*(CIN-SPLIT) + (ci-SPLIT))*256 + y)*256 + x];
        }
        s_in[ci][yy][xx] = v;
    }
    __syncthreads();

    const int ty = tid >> 4, tx = tid & 15;
    float acc[32];
    #pragma unroll
    for (int co = 0; co < 32; co++) acc[co] = bias[co];

    #pragma unroll
    for (int ci = 0; ci < CIN; ci++) {
        #pragma unroll
        for (int ky = 0; ky < 3; ky++)
        #pragma unroll
        for (int kx = 0; kx < 3; kx++) {
            float v = s_in[ci][ty+ky][tx+kx];
            const float* wp = &s_w[(ci*9 + ky*3 + kx)*32];
            #pragma unroll
            for (int co = 0; co < 32; co++) acc[co] = fmaf(v, wp[co], acc[co]);
        }
    }
    const int y = ty0 + ty, x = tx0 + tx;
    size_t base = (((size_t)n*256 + y)*256 + x)*32;
    #pragma unroll
    for (int c = 0; c < 32; c += 8) {
        short8 vv;
        #pragma unroll
        for (int j = 0; j < 8; j++) {
            float v = acc[c+j];
            if (RELU) v = fmaxf(v, 0.f);
            vv[j] = f2bf(v);
        }
        *(short8*)((short*)out + base + c) = vv;
    }
}

// ---------------- weight repack for MFMA convs: [co][ci][tap] f32 -> [tap][co][ci] bf16 ----------------
__global__ __launch_bounds__(256)
void wrepack3(const float* __restrict__ a, const float* __restrict__ b,
              const float* __restrict__ c,
              bf16* __restrict__ oa, bf16* __restrict__ ob, bf16* __restrict__ oc)
{
    int j = blockIdx.x*256 + threadIdx.x;        // 0..27647
    if (j >= 3*9216) return;
    int set = j / 9216, r = j % 9216;
    int tap = r >> 10, rem = r & 1023, co = rem >> 5, ci = rem & 31;
    const float* src = (set == 0) ? a : (set == 1) ? b : c;
    bf16* dst = (set == 0) ? oa : (set == 1) ? ob : oc;
    dst[r] = __float2bfloat16(src[(co*32 + ci)*9 + tap]);
}

// ---------------- heavy conv 3x3 (32->32) via MFMA, channel-last bf16 in/out ----------------
template<bool RELU>
__global__ __launch_bounds__(256)
void conv3x3_mfma(const bf16* __restrict__ in, const bf16* __restrict__ wpk,
                  const float* __restrict__ bias, bf16* __restrict__ out)
{
    const int lane = threadIdx.x & 63, wid = threadIdx.x >> 6;
    const int m = lane & 15, quad = lane >> 4, k0 = quad*8;
    const int n  = blockIdx.z;
    const int x0 = blockIdx.x * 16;
    const int y0 = blockIdx.y * 16 + wid * 4;

    const short* wp = (const short*)wpk;
    short8 bw[2][9];
    #pragma unroll
    for (int g = 0; g < 2; g++)
        #pragma unroll
        for (int tap = 0; tap < 9; tap++)
            bw[g][tap] = *(const short8*)(wp + ((tap*32 + g*16 + m)*32 + k0));
    const float b0 = bias[m], b1 = bias[16 + m];

    const short* inp = (const short*)in + (size_t)n*PLANE*32;
    short* outp = (short*)out + (size_t)n*PLANE*32;

    #pragma unroll
    for (int r = 0; r < 4; r++) {
        const int y = y0 + r;
        f32x4 acc0 = { b0, b0, b0, b0 };
        f32x4 acc1 = { b1, b1, b1, b1 };
        #pragma unroll
        for (int ky = 0; ky < 3; ky++) {
            const int yy = y + ky - 1;
            const bool yok = (unsigned)yy < 256u;
            #pragma unroll
            for (int kx = 0; kx < 3; kx++) {
                const int xp = x0 + kx - 1 + m;
                short8 a = { 0,0,0,0,0,0,0,0 };
                if (yok && (unsigned)xp < 256u)
                    a = *(const short8*)(inp + ((size_t)yy*256 + xp)*32 + k0);
                acc0 = __builtin_amdgcn_mfma_f32_16x16x32_bf16(a, bw[0][ky*3+kx], acc0, 0, 0, 0);
                acc1 = __builtin_amdgcn_mfma_f32_16x16x32_bf16(a, bw[1][ky*3+kx], acc1, 0, 0, 0);
            }
        }
        #pragma unroll
        for (int reg = 0; reg < 4; reg++) {
            int px = x0 + quad*4 + reg;
            size_t idx = ((size_t)y*256 + px)*32;
            float v0 = acc0[reg], v1 = acc1[reg];
            if (RELU) { v0 = fmaxf(v0, 0.f); v1 = fmaxf(v1, 0.f); }
            outp[idx + m]      = f2bf(v0);
            outp[idx + 16 + m] = f2bf(v1);
        }
    }
}

// ---------------- final conv 3x3 (32->1), channel-last input ----------------
__global__ __launch_bounds__(256)
void conv3x3_last(const bf16* __restrict__ in, const float* __restrict__ wgt,
                  const float* __restrict__ bias, float* __restrict__ out)
{
    __shared__ float s_w[288];
    int tid = threadIdx.x;
    for (int i = tid; i < 288; i += 256) s_w[i] = wgt[i];
    __syncthreads();
    int gid = blockIdx.x*256 + tid;
    int n = gid >> 16, h = (gid >> 8) & 255, w = gid & 255;
    const short* inp = (const short*)in + (size_t)n*PLANE*32;
    float sum = bias[0];
    #pragma unroll
    for (int ky = 0; ky < 3; ky++) {
        int yy = h + ky - 1;
        if ((unsigned)yy >= 256u) continue;
        #pragma unroll
        for (int kx = 0; kx < 3; kx++) {
            int xx = w + kx - 1;
            if ((unsigned)xx >= 256u) continue;
            const short8* pp = (const short8*)(inp + ((size_t)yy*256 + xx)*32);
            int tap = ky*3 + kx;
            #pragma unroll
            for (int c4 = 0; c4 < 4; c4++) {
                short8 v = pp[c4];
                #pragma unroll
                for (int j = 0; j < 8; j++)
                    sum = fmaf(bf2f(v[j]), s_w[(c4*8+j)*9 + tap], sum);
            }
        }
    }
    out[gid] = sum;
}

// ---------------- squared neighbor diffs over 32 channels, channel-last ----------------
template<bool ACCUM>
__global__ __launch_bounds__(256)
void dvdh_cl(const bf16* __restrict__ f, float* __restrict__ dv, float* __restrict__ dh)
{
    int bid = blockIdx.x;
    int n = bid >> 8, i = bid & 255, j = threadIdx.x;
    const short8* pc = (const short8*)((const short*)f + (((size_t)n*256 + i)*256 + j)*32);
    const short8* pr = (j < 255) ? pc + 4    : pc;
    const short8* pd = (i < 255) ? pc + 1024 : pc;
    float adv = 0.f, adh = 0.f;
    #pragma unroll
    for (int c4 = 0; c4 < 4; c4++) {
        short8 sc = pc[c4], sr = pr[c4], sd = pd[c4];
        #pragma unroll
        for (int e = 0; e < 8; e++) {
            float fc = bf2f(sc[e]);
            float d1 = bf2f(sr[e]) - fc;
            float d2 = bf2f(sd[e]) - fc;
            adh = fmaf(d1, d1, adh);
            adv = fmaf(d2, d2, adv);
        }
    }
    int o = (n*256 + i)*256 + j;
    if (ACCUM) { dv[o] += adv; dh[o] += adh; }
    else       { dv[o]  = adv; dh[o]  = adh; }
}

// ---------------- affinity: packed bf16 (wv,wh) for CG + 5-plane fp32 output ----------------
__global__ __launch_bounds__(256)
void aff2_kernel(const float* __restrict__ dv, const float* __restrict__ dh,
                 const float* __restrict__ llam, const float* __restrict__ lmu,
                 unsigned* __restrict__ wvh, float* __restrict__ aff)
{
    int bid = blockIdx.x;
    int n = bid >> 8, h = bid & 255, w = threadIdx.x;
    float mu = expf(lmu[0]), lam = expf(llam[0]);
    int rb = (n*256 + h)*256 + w;
    float wvv = (h < 255) ? expf(-mu * dv[rb]) : 0.f;
    float whv = (w < 255) ? expf(-mu * dh[rb]) : 0.f;
    unsigned pv = (unsigned)(unsigned short)f2bf(wvv);
    unsigned ph = (unsigned)(unsigned short)f2bf(whv);
    wvh[rb] = pv | (ph << 16);
    float w_up = (h > 0) ? expf(-mu * dv[rb - 256]) : 0.f;
    float w_lf = (w > 0) ? expf(-mu * dh[rb - 1])   : 0.f;
    float ctr  = w_up + wvv + w_lf + whv + lam;
    float* a = aff + ((size_t)n*5)*PLANE + h*256 + w;
    a[0]        = w_up;
    a[PLANE]    = wvv;
    a[2*PLANE]  = w_lf;
    a[3*PLANE]  = whv;
    a[4*PLANE]  = ctr;
}

// ============ persistent CG: 512 workers, 2-level hierarchical all-reduce ============
// 16 img x 32 tiles of 64x32, 256 thr, __launch_bounds__(256,2): VGPR ~84 (no spill),
// 2 blocks/CU capacity -> all 512 co-resident. x,r,p,Ap in registers (8 px/thread).
// Reduction: 4 groups x 128 blocks, split EXACTLY on round-5's wave-subtree boundary:
// group leader (wb%128==0, ordinary worker) wave 0 polls its 128 member flags (2/lane),
// lane pairing + shfl tree identical to the old per-wave tree -> lane0 = old wave
// partial -> one 64B result line (3 floats + seq flag). Every block polls only the 4
// group lines and combines ((g0+g1)+g2)+g3 left-assoc -> BIT-IDENTICAL scalars to r5.
// Coherence-point request count drops ~40x vs r5's flat replicated gather.
// Zero atomic RMWs. part[]/edges double-buffered by seq parity as before.
__global__ __launch_bounds__(256, 2)
void cg_persist(const unsigned* __restrict__ wvh, const float* __restrict__ mask,
                const float* __restrict__ src, const float* __restrict__ ybic,
                const float* __restrict__ llam, float* __restrict__ xout,
                float* __restrict__ ebuf0, float* __restrict__ ebuf1,
                float* __restrict__ part, unsigned* __restrict__ arrive,
                float* __restrict__ res)
{
    __shared__ float s_pn[66][34];
    __shared__ float s_part[256], s_bs[32];
    __shared__ float s_w3[12], s_g[16];

    const int tid = threadIdx.x;
    const int wb = blockIdx.x;
    const int n = wb >> 5, t = wb & 31;
    const int tyo = (t >> 3) * 64, txo = (t & 7) * 32;
    const int tx = tid & 31, tyb = tid >> 5;
    const int w = txo + tx;
    const float lam = expf(llam[0]);
    const bool is_leader = ((wb & 127) == 0);

    const unsigned* wn = wvh + (size_t)n*PLANE;
    const float* ybn = ybic + (size_t)n*PLANE;

    // per-thread stencil constants
    int idx[8];
    unsigned wc[8], wu[8], wl[8];
    float c1[8], rhs[8];
    #pragma unroll
    for (int i = 0; i < 8; i++) {
        int hhi = tyo + tyb + 8*i;
        idx[i] = hhi*256 + w;
        wc[i] = wn[idx[i]];
        wu[i] = (hhi > 0) ? wn[idx[i]-256] : 0u;
        wl[i] = (w > 0)   ? wn[idx[i]-1]   : 0u;
        int bi = n*1024 + (hhi>>3)*32 + (w>>3);
        float mv = mask[bi];
        c1[i]  = lam*mv*(1.f/4096.f);
        rhs[i] = lam*mv*src[bi]*(1.f/64.f);
    }

    // halo-cell ownership: tid<192 owns one cell of the 1-px ring (no corners).
    // edge array layout per block: [0,32)=top row, [32,64)=bottom row,
    //                              [64,128)=left col, [128,192)=right col
    const bool hthr = (tid < 192);
    int hy = 0, hx = 0; bool hin = false; int nb = 0, eoff = 0;
    if (hthr) {
        if      (tid < 32)  { hy = tyo - 1;         hx = txo + tid;
                              nb = wb - 8; eoff = 32 + tid; }            // up <- above's bottom
        else if (tid < 64)  { hy = tyo + 64;        hx = txo + (tid-32);
                              nb = wb + 8; eoff = tid - 32; }            // down <- below's top
        else if (tid < 128) { hy = tyo + (tid-64);  hx = txo - 1;
                              nb = wb - 1; eoff = 128 + (tid-64); }      // left <- left's right col
        else                { hy = tyo + (tid-128); hx = txo + 32;
                              nb = wb + 1; eoff = 64 + (tid-128); }      // right <- right's left col
        hin = (hy >= 0 && hy < 256 && hx >= 0 && hx < 256);
    }
    const int hsy = hy - tyo + 1, hsx = hx - txo + 1;

    // avgpool(8x8) of the LDS tile -> s_bs[32]
    #define POOL_BLOCK() do { \
        __syncthreads(); \
        { int segrow_ = tid >> 2, segcol_ = tid & 3; \
          const float* rw_ = &s_pn[1 + segrow_][1 + segcol_*8]; \
          s_part[tid] = rw_[0]+rw_[1]+rw_[2]+rw_[3]+rw_[4]+rw_[5]+rw_[6]+rw_[7]; } \
        __syncthreads(); \
        if (tid < 32) { int brow_ = tid >> 2, bcol_ = tid & 3; float s_ = 0.f; \
          _Pragma("unroll") \
          for (int rr_ = 0; rr_ < 8; rr_++) s_ += s_part[(brow_*8 + rr_)*4 + bcol_]; \
          s_bs[tid] = s_; } \
        __syncthreads(); \
    } while (0)

    // publish tile-border values of arr[] to compact edge array (agent-scope)
    #define PUBLISH_E(arr, ebase) do { \
        float* eb_ = (ebase) + (size_t)wb*192; \
        if (tyb == 0) stg_ag(eb_ + tx, arr[0]); \
        if (tyb == 7) stg_ag(eb_ + 32 + tx, arr[7]); \
        if (tx == 0) { _Pragma("unroll") \
            for (int i_ = 0; i_ < 8; i_++) stg_ag(eb_ + 64 + tyb + 8*i_, arr[i_]); } \
        if (tx == 31){ _Pragma("unroll") \
            for (int i_ = 0; i_ < 8; i_++) stg_ag(eb_ + 128 + tyb + 8*i_, arr[i_]); } \
    } while (0)

    auto matvec = [&](int i) -> float {
        int yy = 1 + tyb + 8*i, xx = 1 + tx;
        float wvd = bf2f((short)(wc[i] & 0xffff));
        float whr = bf2f((short)(wc[i] >> 16));
        float wvu = bf2f((short)(wu[i] & 0xffff));
        float whl = bf2f((short)(wl[i] >> 16));
        float s = wvu*s_pn[yy-1][xx] + wvd*s_pn[yy+1][xx]
                + whl*s_pn[yy][xx-1] + whr*s_pn[yy][xx+1];
        float deg = wvu+wvd+whl+whr;
        return deg*s_pn[yy][xx] - s + c1[i]*s_bs[i*4 + (tx>>3)];
    };

    // block 3-dot reduce -> publish partials (parity seq&1) + arrival flag.
    auto publish_red = [&](unsigned seq, float va, float vb, float vc){
        #pragma unroll
        for (int o = 32; o > 0; o >>= 1) {
            va += __shfl_down(va, o, 64);
            vb += __shfl_down(vb, o, 64);
            vc += __shfl_down(vc, o, 64);
        }
        asm volatile("s_waitcnt vmcnt(0)" ::: "memory");  // per-wave edge-store drain
        __syncthreads();
        if ((tid & 63) == 0) { int wv = tid >> 6; s_w3[wv*3]=va; s_w3[wv*3+1]=vb; s_w3[wv*3+2]=vc; }
        __syncthreads();
        if (tid == 0) {
            float* pp = part + (size_t)(seq & 1)*1536;
            stg_ag(pp + wb,        s_w3[0]+s_w3[3]+s_w3[6]+s_w3[9]);
            stg_ag(pp + 512 + wb,  s_w3[1]+s_w3[4]+s_w3[7]+s_w3[10]);
            stg_ag(pp + 1024 + wb, s_w3[2]+s_w3[5]+s_w3[8]+s_w3[11]);
            asm volatile("s_waitcnt vmcnt(0)" ::: "memory");
            stu_ag(&arrive[wb], seq);
        }
    };

    // 2-level barrier + 3-dot grid reduction (parity seq&1).
    // Leader wave0: gather 128 member partials with the r5 lane/shfl tree.
    // All blocks: poll 4 group lines, combine left-assoc. Bit-identical to r5.
    float o0, o1, o2;
    auto allred = [&](unsigned seq){
        float* resp = res + (size_t)(seq & 1)*64;    // 4 lines x 16 floats
        if (is_leader && tid < 64) {
            const unsigned m0 = (unsigned)wb + 2*tid, m1 = m0 + 1;
            while (ldu_ag(&arrive[m0]) < seq) __builtin_amdgcn_s_sleep(2);
            while (ldu_ag(&arrive[m1]) < seq) __builtin_amdgcn_s_sleep(2);
            const float* pp = part + (size_t)(seq & 1)*1536;
            float pa = ldg_ag(pp + m0)        + ldg_ag(pp + m1);
            float pb = ldg_ag(pp + 512 + m0)  + ldg_ag(pp + 512 + m1);
            float pc = ldg_ag(pp + 1024 + m0) + ldg_ag(pp + 1024 + m1);
            #pragma unroll
            for (int o = 32; o > 0; o >>= 1) {
                pa += __shfl_down(pa, o, 64);
                pb += __shfl_down(pb, o, 64);
                pc += __shfl_down(pc, o, 64);
            }
            if (tid == 0) {
                float* rl = resp + (wb >> 7)*16;
                stg_ag(rl+0, pa); stg_ag(rl+1, pb); stg_ag(rl+2, pc);
                asm volatile("s_waitcnt vmcnt(0)" ::: "memory");
                stu_ag((unsigned*)(rl+3), seq);
            }
        }
        if (tid < 4) {
            const float* rl = resp + tid*16;
            while (ldu_ag((const unsigned*)(rl+3)) < seq) __builtin_amdgcn_s_sleep(1);
            s_g[tid*4+0] = ldg_ag(rl+0);
            s_g[tid*4+1] = ldg_ag(rl+1);
            s_g[tid*4+2] = ldg_ag(rl+2);
        }
        __syncthreads();
        o0 = ((s_g[0]+s_g[4])+s_g[8])+s_g[12];
        o1 = ((s_g[1]+s_g[5])+s_g[9])+s_g[13];
        o2 = ((s_g[2]+s_g[6])+s_g[10])+s_g[14];
    };

    float xv[8], rv[8], pv[8], apv[8];
    float rh = 0.f, phh = 0.f;

    // ---------- phase 1: x0 = ybic, r0 = p0 = b - A x0 (halo via direct global reads);
    //            publish r0 edges -> ebuf1; flag=1; hierarchical flags-only barrier ----------
    #pragma unroll
    for (int i = 0; i < 8; i++) {
        xv[i] = ybn[idx[i]];
        s_pn[1 + tyb + 8*i][1 + tx] = xv[i];
    }
    if (hthr) s_pn[hsy][hsx] = hin ? ybn[hy*256 + hx] : 0.f;
    POOL_BLOCK();
    float g0t = 0.f;
    #pragma unroll
    for (int i = 0; i < 8; i++) {
        float ax = matvec(i);
        float r0 = rhs[i] - ax;
        rv[i] = r0; pv[i] = r0;
        g0t += r0*r0;
    }
    PUBLISH_E(pv, ebuf1);
    asm volatile("s_waitcnt vmcnt(0)" ::: "memory");
    __syncthreads();
    if (tid == 0) stu_ag(&arrive[wb], 1u);
    {   // flags-only 2-level barrier, seq=1 (parity 1)
        if (is_leader && tid < 64) {
            const unsigned m0 = (unsigned)wb + 2*tid, m1 = m0 + 1;
            while (ldu_ag(&arrive[m0]) < 1u) __builtin_amdgcn_s_sleep(2);
            while (ldu_ag(&arrive[m1]) < 1u) __builtin_amdgcn_s_sleep(2);
            if (tid == 0)
                stu_ag((unsigned*)(res + 64 + (wb >> 7)*16 + 3), 1u);
        }
        if (tid < 4) {
            const unsigned* fl = (const unsigned*)(res + 64 + tid*16 + 3);
            while (ldu_ag(fl) < 1u) __builtin_amdgcn_s_sleep(1);
        }
        __syncthreads();
    }

    // ---------- phase 2 (k=0): halo r0 from neighbor edges; Ap0 = A p0;
    //            publish Ap0 edges -> ebuf0; parts (g0,pAp0,ApAp0) flag=2 ----------
    {
        float hv = 0.f;
        if (hthr && hin) hv = ldg_ag(ebuf1 + (size_t)nb*192 + eoff);
        if (hthr) { rh = hv; phh = hv; s_pn[hsy][hsx] = phh; }
        #pragma unroll
        for (int i = 0; i < 8; i++) s_pn[1 + tyb + 8*i][1 + tx] = pv[i];
        POOL_BLOCK();
        float pap = 0.f, apap = 0.f;
        #pragma unroll
        for (int i = 0; i < 8; i++) {
            float ap = matvec(i);
            apv[i] = ap;
            pap  += pv[i]*ap;
            apap += ap*ap;
        }
        PUBLISH_E(apv, ebuf0);
        publish_red(2u, g0t, pap, apap);
    }

    // ---------- main loop k=1..99 (phase seq = k+2; allred(k+1) -> prev scalars) ----------
    for (int k = 1; k <= 99; k++) {
        float* ebR = ((k+1) & 1) ? ebuf1 : ebuf0;   // neighbor Ap_{k-1} edges (seq k+1)
        float* ebW = ((k+2) & 1) ? ebuf1 : ebuf0;   // our Ap_k edges (seq k+2)

        allred((unsigned)(k + 1));                  // -> (g_{k-1}, pAp_{k-1}, ApAp_{k-1})
        float alpha = o0 / o1;
        float beta  = (alpha*alpha*o2 - o0) / o0;

        // halo load overlaps the interior update below (hv used last)
        float hv = 0.f;
        if (hthr && hin) hv = ldg_ag(ebR + (size_t)nb*192 + eoff);

        float gsum = 0.f;
        #pragma unroll
        for (int i = 0; i < 8; i++) {
            float rN = fmaf(-alpha, apv[i], rv[i]);
            xv[i] = fmaf(alpha, pv[i], xv[i]);
            float pN = fmaf(beta, pv[i], rN);
            rv[i] = rN; pv[i] = pN;
            gsum += rN*rN;
            s_pn[1 + tyb + 8*i][1 + tx] = pN;
        }
        if (hthr) {
            rh  = fmaf(-alpha, hv, rh);
            phh = fmaf(beta, phh, rh);
            s_pn[hsy][hsx] = phh;
        }
        POOL_BLOCK();
        float pap = 0.f, apap = 0.f;
        #pragma unroll
        for (int i = 0; i < 8; i++) {
            float ap = matvec(i);
            apv[i] = ap;
            pap  += pv[i]*ap;
            apap += ap*ap;
        }
        PUBLISH_E(apv, ebW);
        publish_red((unsigned)(k + 2), gsum, pap, apap);
    }

    // ---------- tail: x += alpha_100 * p_99 ----------
    allred(101u);   // -> (g_99, pAp_99, ApAp_99)
    float alphaT = o0 / o1;
    float* xn = xout + (size_t)n*PLANE;
    #pragma unroll
    for (int i = 0; i < 8; i++) xn[idx[i]] = fmaf(alphaT, pv[i], xv[i]);

    #undef POOL_BLOCK
    #undef PUBLISH_E
}

// ---------------- host ----------------
extern "C" void kernel_launch(void* const* d_in, const int* in_sizes, int n_in,
                              void* d_out, int out_size, void* d_ws, size_t ws_size,
                              hipStream_t stream)
{
    (void)in_sizes; (void)n_in; (void)out_size; (void)ws_size;
    const float* guide = (const float*)d_in[0];
    const float* source= (const float*)d_in[1];
    const float* mask  = (const float*)d_in[2];
    const float* ybic  = (const float*)d_in[3];
    const float* gw1 = (const float*)d_in[4];  const float* gb1 = (const float*)d_in[5];
    const float* gw2 = (const float*)d_in[6];  const float* gb2 = (const float*)d_in[7];
    const float* sw1 = (const float*)d_in[8];  const float* sb1 = (const float*)d_in[9];
    const float* sw2 = (const float*)d_in[10]; const float* sb2 = (const float*)d_in[11];
    const float* vw1 = (const float*)d_in[12]; const float* vb1 = (const float*)d_in[13];
    const float* vw2 = (const float*)d_in[14]; const float* vb2 = (const float*)d_in[15];
    const float* vw3 = (const float*)d_in[16]; const float* vb3 = (const float*)d_in[17];
    const float* llam = (const float*)d_in[18];
    const float* lmu  = (const float*)d_in[19];

    float* out     = (float*)d_out;
    float* x_out   = out;                 // y_pred (16,1,256,256)
    float* var_out = out + 1048576;       // var
    float* aff_out = out + 2097152;       // aff (16,5,256,256)

    // ---- workspace layout ----
    char* ws = (char*)d_ws;
    float*    res   = (float*)ws;                       // 2 parity x 4 lines x 16 floats [0,512)
    float*    part  = (float*)(ws + 2048);              // 2 parity x 1536 floats -> [2048, 14336)
    unsigned* arrive= (unsigned*)(ws + 14336);          // 512 uints -> [14336, 16384)
    bf16*     wpk1  = (bf16*)(ws + 16384);              // 18 KiB each
    bf16*     wpk2  = (bf16*)(ws + 34816);
    bf16*     wpk3  = (bf16*)(ws + 53248);              // ends at 71680
    unsigned* wvh   = (unsigned*)(ws + 131072);         // [128 KiB, 128 KiB + 4 MiB)
    char*     A     = ws + 131072 + (size_t)NB*PLANE*4; // shared region
    // conv-phase mapping of A:
    bf16*  tmp1 = (bf16*)(A);                                  // 64 MiB
    bf16*  tmp2 = (bf16*)(A + (size_t)NB*32*PLANE*2);          // 64 MiB
    float* dv   = (float*)(A + (size_t)NB*32*PLANE*4);         // 4 MiB
    float* dh   = (float*)(A + (size_t)NB*32*PLANE*4 + (size_t)NB*PLANE*4);
    // CG-phase mapping of A (conv temporaries dead by then): compact edge buffers
    float* ebuf0 = (float*)A;                                  // 512*192 floats
    float* ebuf1 = (float*)(A + (size_t)512*192*4);

    dim3 cgrid(16, 16, NB);

    // zero res lines + arrive flags (part never read before first write)
    hipMemsetAsync(ws, 0, 2048, stream);
    hipMemsetAsync(arrive, 0, 2048, stream);

    // repack the three 32->32 conv weights into MFMA fragment layout
    wrepack3<<<108,256,0,stream>>>(gw2, sw2, vw2, wpk1, wpk2, wpk3);

    // feature branch g = conv(relu(conv(guide)))
    conv3x3_first<3,3,true><<<cgrid,256,0,stream>>>(guide, guide, gw1, gb1, tmp1);
    conv3x3_mfma<false><<<cgrid,256,0,stream>>>(tmp1, wpk1, gb2, tmp2);
    dvdh_cl<false><<<4096,256,0,stream>>>(tmp2, dv, dh);
    // feature branch s = conv(relu(conv(y_bicubic)))
    conv3x3_first<1,1,true><<<cgrid,256,0,stream>>>(ybic, ybic, sw1, sb1, tmp1);
    conv3x3_mfma<false><<<cgrid,256,0,stream>>>(tmp1, wpk2, sb2, tmp2);
    dvdh_cl<true><<<4096,256,0,stream>>>(tmp2, dv, dh);
    aff2_kernel<<<4096,256,0,stream>>>(dv, dh, llam, lmu, wvh, aff_out);
    // variance branch
    conv3x3_first<4,3,true><<<cgrid,256,0,stream>>>(guide, ybic, vw1, vb1, tmp1);
    conv3x3_mfma<true><<<cgrid,256,0,stream>>>(tmp1, wpk3, vb2, tmp2);
    conv3x3_last<<<4096,256,0,stream>>>(tmp2, vw3, vb3, var_out);

    // CG: ONE persistent dispatch — 512 workers, 2-level hierarchical barrier
    cg_persist<<<512,256,0,stream>>>(wvh, mask, source, ybic, llam, x_out,
                                     ebuf0, ebuf1, part, arrive, res);
}

// Round 7
// 914.492 us; speedup vs baseline: 1.7210x; 1.5775x over previous
//
#include <hip/hip_runtime.h>
#include <hip/hip_bf16.h>

typedef __hip_bfloat16 bf16;
typedef __attribute__((ext_vector_type(8))) short short8;
typedef __attribute__((ext_vector_type(4))) float f32x4;

#define NB 16
#define PLANE (256*256)

static __device__ __forceinline__ short f2bf(float v){
    __hip_bfloat16 h = __float2bfloat16(v);
    short s; __builtin_memcpy(&s, &h, 2); return s;
}
static __device__ __forceinline__ float bf2f(short s){
    union { unsigned u; float f; } cv;
    cv.u = ((unsigned)(unsigned short)s) << 16; return cv.f;
}

// agent-scope (cross-XCD coherent, uncached) accesses — bypass per-XCD L2
static __device__ __forceinline__ void  stg_ag(float* p, float v){
    __hip_atomic_store(p, v, __ATOMIC_RELAXED, __HIP_MEMORY_SCOPE_AGENT);
}
static __device__ __forceinline__ float ldg_ag(const float* p){
    return __hip_atomic_load(p, __ATOMIC_RELAXED, __HIP_MEMORY_SCOPE_AGENT);
}
// packed 16B coherent store/load: payload (3 floats) + seq flag land/observe atomically
// (single 16B-aligned dwordx4 = one coherence-point transaction)
static __device__ __forceinline__ void stg4_ag(float* p, f32x4 v){
    asm volatile("global_store_dwordx4 %0, %1, off sc0 sc1" :: "v"(p), "v"(v) : "memory");
}
static __device__ __forceinline__ f32x4 ldg4_ag(const float* p){
    f32x4 r;
    asm volatile("global_load_dwordx4 %0, %1, off sc0 sc1\n\ts_waitcnt vmcnt(0)"
                 : "=v"(r) : "v"(p) : "memory");
    return r;
}

// ---------------- first-layer conv 3x3 (small CIN, VALU), output channel-last bf16 ----------------
template<int CIN, int SPLIT, bool RELU>
__global__ __launch_bounds__(256)
void conv3x3_first(const float* __restrict__ in, const float* __restrict__ in2,
                   const float* __restrict__ wgt, const float* __restrict__ bias,
                   bf16* __restrict__ out)
{
    __shared__ float s_in[CIN][18][18];
    __shared__ float s_w[CIN*9*32];
    const int n  = blockIdx.z;
    const int ty0 = blockIdx.y * 16, tx0 = blockIdx.x * 16;
    const int tid = threadIdx.x;

    for (int idx = tid; idx < CIN*9*32; idx += 256) {
        int co = idx & 31; int rest = idx >> 5;     // rest = ci*9 + k
        s_w[idx] = wgt[(co*CIN + rest/9)*9 + rest%9];
    }
    for (int idx = tid; idx < CIN*18*18; idx += 256) {
        int ci = idx / (18*18); int rr = idx % (18*18);
        int yy = rr / 18, xx = rr % 18;
        int y = ty0 + yy - 1, x = tx0 + xx - 1;
        float v = 0.f;
        if (y >= 0 && y < 256 && x >= 0 && x < 256) {
            if (ci < SPLIT) v = in [((size_t)(n*SPLIT + ci)*256 + y)*256 + x];
            else            v = in2[((size_t)(n*(CIN-SPLIT) + (ci-SPLIT))*256 + y)*256 + x];
        }
        s_in[ci][yy][xx] = v;
    }
    __syncthreads();

    const int ty = tid >> 4, tx = tid & 15;
    float acc[32];
    #pragma unroll
    for (int co = 0; co < 32; co++) acc[co] = bias[co];

    #pragma unroll
    for (int ci = 0; ci < CIN; ci++) {
        #pragma unroll
        for (int ky = 0; ky < 3; ky++)
        #pragma unroll
        for (int kx = 0; kx < 3; kx++) {
            float v = s_in[ci][ty+ky][tx+kx];
            const float* wp = &s_w[(ci*9 + ky*3 + kx)*32];
            #pragma unroll
            for (int co = 0; co < 32; co++) acc[co] = fmaf(v, wp[co], acc[co]);
        }
    }
    const int y = ty0 + ty, x = tx0 + tx;
    size_t base = (((size_t)n*256 + y)*256 + x)*32;
    #pragma unroll
    for (int c = 0; c < 32; c += 8) {
        short8 vv;
        #pragma unroll
        for (int j = 0; j < 8; j++) {
            float v = acc[c+j];
            if (RELU) v = fmaxf(v, 0.f);
            vv[j] = f2bf(v);
        }
        *(short8*)((short*)out + base + c) = vv;
    }
}

// ---------------- weight repack for MFMA convs: [co][ci][tap] f32 -> [tap][co][ci] bf16 ----------------
__global__ __launch_bounds__(256)
void wrepack3(const float* __restrict__ a, const float* __restrict__ b,
              const float* __restrict__ c,
              bf16* __restrict__ oa, bf16* __restrict__ ob, bf16* __restrict__ oc)
{
    int j = blockIdx.x*256 + threadIdx.x;        // 0..27647
    if (j >= 3*9216) return;
    int set = j / 9216, r = j % 9216;
    int tap = r >> 10, rem = r & 1023, co = rem >> 5, ci = rem & 31;
    const float* src = (set == 0) ? a : (set == 1) ? b : c;
    bf16* dst = (set == 0) ? oa : (set == 1) ? ob : oc;
    dst[r] = __float2bfloat16(src[(co*32 + ci)*9 + tap]);
}

// ---------------- heavy conv 3x3 (32->32) via MFMA, LDS-staged input ----------------
// Input tile (18x18 halo, 32ch, zero-padded) staged once in LDS, channel-slice-major:
// s_a[slice q][18][18][8ch], slice stride 2640 shorts (5280B, +96B pad -> quad bank
// shift 8 -> uniform 2-way LDS aliasing = free). MFMA a-fragments via ds_read_b128.
// Bit-identical to the unstaged version (same MFMA sequence, zeros outside image).
template<bool RELU>
__global__ __launch_bounds__(256)
void conv3x3_mfma(const bf16* __restrict__ in, const bf16* __restrict__ wpk,
                  const float* __restrict__ bias, bf16* __restrict__ out)
{
    __shared__ __align__(16) short s_a[4*2640];
    const int tid = threadIdx.x;
    const int lane = tid & 63, wid = tid >> 6;
    const int m = lane & 15, quad = lane >> 4, k0 = quad*8;
    const int n  = blockIdx.z;
    const int x0 = blockIdx.x * 16;
    const int y0 = blockIdx.y * 16;

    const short* inp = (const short*)in + (size_t)n*PLANE*32;
    short* outp = (short*)out + (size_t)n*PLANE*32;

    // stage: c = px*4 + q -> consecutive tids read contiguous 16B chunks (coalesced)
    for (int c = tid; c < 1296; c += 256) {
        int q = c & 3, px = c >> 2;
        int yy = px / 18, xx = px - yy*18;
        int gy = y0 + yy - 1, gx = x0 + xx - 1;
        short8 v = {0,0,0,0,0,0,0,0};
        if ((unsigned)gy < 256u && (unsigned)gx < 256u)
            v = *(const short8*)(inp + ((size_t)(gy*256 + gx))*32 + q*8);
        *(short8*)(s_a + q*2640 + (yy*18 + xx)*8) = v;
    }

    const short* wp = (const short*)wpk;
    short8 bw[2][9];
    #pragma unroll
    for (int g = 0; g < 2; g++)
        #pragma unroll
        for (int tap = 0; tap < 9; tap++)
            bw[g][tap] = *(const short8*)(wp + ((tap*32 + g*16 + m)*32 + k0));
    const float b0 = bias[m], b1 = bias[16 + m];
    __syncthreads();

    const short* sa = s_a + quad*2640;
    #pragma unroll
    for (int r = 0; r < 4; r++) {
        const int lr = wid*4 + r;                       // local row 0..15
        f32x4 acc0 = { b0, b0, b0, b0 };
        f32x4 acc1 = { b1, b1, b1, b1 };
        #pragma unroll
        for (int ky = 0; ky < 3; ky++)
        #pragma unroll
        for (int kx = 0; kx < 3; kx++) {
            short8 a = *(const short8*)(sa + ((lr+ky)*18 + (m+kx))*8);
            acc0 = __builtin_amdgcn_mfma_f32_16x16x32_bf16(a, bw[0][ky*3+kx], acc0, 0, 0, 0);
            acc1 = __builtin_amdgcn_mfma_f32_16x16x32_bf16(a, bw[1][ky*3+kx], acc1, 0, 0, 0);
        }
        const int y = y0 + lr;
        #pragma unroll
        for (int reg = 0; reg < 4; reg++) {
            int px = x0 + quad*4 + reg;
            size_t idx = ((size_t)y*256 + px)*32;
            float v0 = acc0[reg], v1 = acc1[reg];
            if (RELU) { v0 = fmaxf(v0, 0.f); v1 = fmaxf(v1, 0.f); }
            outp[idx + m]      = f2bf(v0);
            outp[idx + 16 + m] = f2bf(v1);
        }
    }
}

// ---------------- final conv 3x3 (32->1), channel-last input ----------------
__global__ __launch_bounds__(256)
void conv3x3_last(const bf16* __restrict__ in, const float* __restrict__ wgt,
                  const float* __restrict__ bias, float* __restrict__ out)
{
    __shared__ float s_w[288];
    int tid = threadIdx.x;
    for (int i = tid; i < 288; i += 256) s_w[i] = wgt[i];
    __syncthreads();
    int gid = blockIdx.x*256 + tid;
    int n = gid >> 16, h = (gid >> 8) & 255, w = gid & 255;
    const short* inp = (const short*)in + (size_t)n*PLANE*32;
    float sum = bias[0];
    #pragma unroll
    for (int ky = 0; ky < 3; ky++) {
        int yy = h + ky - 1;
        if ((unsigned)yy >= 256u) continue;
        #pragma unroll
        for (int kx = 0; kx < 3; kx++) {
            int xx = w + kx - 1;
            if ((unsigned)xx >= 256u) continue;
            const short8* pp = (const short8*)(inp + ((size_t)yy*256 + xx)*32);
            int tap = ky*3 + kx;
            #pragma unroll
            for (int c4 = 0; c4 < 4; c4++) {
                short8 v = pp[c4];
                #pragma unroll
                for (int j = 0; j < 8; j++)
                    sum = fmaf(bf2f(v[j]), s_w[(c4*8+j)*9 + tap], sum);
            }
        }
    }
    out[gid] = sum;
}

// ---------------- squared neighbor diffs over 32 channels, channel-last ----------------
template<bool ACCUM>
__global__ __launch_bounds__(256)
void dvdh_cl(const bf16* __restrict__ f, float* __restrict__ dv, float* __restrict__ dh)
{
    int bid = blockIdx.x;
    int n = bid >> 8, i = bid & 255, j = threadIdx.x;
    const short8* pc = (const short8*)((const short*)f + (((size_t)n*256 + i)*256 + j)*32);
    const short8* pr = (j < 255) ? pc + 4    : pc;
    const short8* pd = (i < 255) ? pc + 1024 : pc;
    float adv = 0.f, adh = 0.f;
    #pragma unroll
    for (int c4 = 0; c4 < 4; c4++) {
        short8 sc = pc[c4], sr = pr[c4], sd = pd[c4];
        #pragma unroll
        for (int e = 0; e < 8; e++) {
            float fc = bf2f(sc[e]);
            float d1 = bf2f(sr[e]) - fc;
            float d2 = bf2f(sd[e]) - fc;
            adh = fmaf(d1, d1, adh);
            adv = fmaf(d2, d2, adv);
        }
    }
    int o = (n*256 + i)*256 + j;
    if (ACCUM) { dv[o] += adv; dh[o] += adh; }
    else       { dv[o]  = adv; dh[o]  = adh; }
}

// ---------------- affinity: packed bf16 (wv,wh) for CG + 5-plane fp32 output ----------------
__global__ __launch_bounds__(256)
void aff2_kernel(const float* __restrict__ dv, const float* __restrict__ dh,
                 const float* __restrict__ llam, const float* __restrict__ lmu,
                 unsigned* __restrict__ wvh, float* __restrict__ aff)
{
    int bid = blockIdx.x;
    int n = bid >> 8, h = bid & 255, w = threadIdx.x;
    float mu = expf(lmu[0]), lam = expf(llam[0]);
    int rb = (n*256 + h)*256 + w;
    float wvv = (h < 255) ? expf(-mu * dv[rb]) : 0.f;
    float whv = (w < 255) ? expf(-mu * dh[rb]) : 0.f;
    unsigned pv = (unsigned)(unsigned short)f2bf(wvv);
    unsigned ph = (unsigned)(unsigned short)f2bf(whv);
    wvh[rb] = pv | (ph << 16);
    float w_up = (h > 0) ? expf(-mu * dv[rb - 256]) : 0.f;
    float w_lf = (w > 0) ? expf(-mu * dh[rb - 1])   : 0.f;
    float ctr  = w_up + wvv + w_lf + whv + lam;
    float* a = aff + ((size_t)n*5)*PLANE + h*256 + w;
    a[0]        = w_up;
    a[PLANE]    = wvv;
    a[2*PLANE]  = w_lf;
    a[3*PLANE]  = whv;
    a[4*PLANE]  = ctr;
}

// ============ persistent CG: 512 workers, 2-level reduce, PACKED 16B sync lines ============
// As round 6, but each sync hop is ONE 16B coherent transaction carrying payload+seq:
// worker part line = {pa,pb,pc,seq}; group result line = {fa,fb,fc,seq}. Pollers get
// detection AND values from the same dwordx4 load -> sync chain drops from ~7 to ~3
// dependent uncached round-trips per phase. Reduction pairing/tree order unchanged
// from r6 -> bit-identical scalars -> identical output.
__global__ __launch_bounds__(256, 2)
void cg_persist(const unsigned* __restrict__ wvh, const float* __restrict__ mask,
                const float* __restrict__ src, const float* __restrict__ ybic,
                const float* __restrict__ llam, float* __restrict__ xout,
                float* __restrict__ ebuf0, float* __restrict__ ebuf1,
                float* __restrict__ part4, float* __restrict__ res4)
{
    __shared__ float s_pn[66][34];
    __shared__ float s_part[256], s_bs[32];
    __shared__ float s_w3[12];
    __shared__ __align__(16) float s_g[16];

    const int tid = threadIdx.x;
    const int wb = blockIdx.x;
    const int n = wb >> 5, t = wb & 31;
    const int tyo = (t >> 3) * 64, txo = (t & 7) * 32;
    const int tx = tid & 31, tyb = tid >> 5;
    const int w = txo + tx;
    const float lam = expf(llam[0]);
    const bool is_leader = ((wb & 127) == 0);

    const unsigned* wn = wvh + (size_t)n*PLANE;
    const float* ybn = ybic + (size_t)n*PLANE;

    // per-thread stencil constants
    int idx[8];
    unsigned wc[8], wu[8], wl[8];
    float c1[8], rhs[8];
    #pragma unroll
    for (int i = 0; i < 8; i++) {
        int hhi = tyo + tyb + 8*i;
        idx[i] = hhi*256 + w;
        wc[i] = wn[idx[i]];
        wu[i] = (hhi > 0) ? wn[idx[i]-256] : 0u;
        wl[i] = (w > 0)   ? wn[idx[i]-1]   : 0u;
        int bi = n*1024 + (hhi>>3)*32 + (w>>3);
        float mv = mask[bi];
        c1[i]  = lam*mv*(1.f/4096.f);
        rhs[i] = lam*mv*src[bi]*(1.f/64.f);
    }

    // halo-cell ownership (1-px ring, no corners); nb = owning neighbor, eoff = slot
    const bool hthr = (tid < 192);
    int hy = 0, hx = 0; bool hin = false; int nb = 0, eoff = 0;
    if (hthr) {
        if      (tid < 32)  { hy = tyo - 1;         hx = txo + tid;
                              nb = wb - 8; eoff = 32 + tid; }
        else if (tid < 64)  { hy = tyo + 64;        hx = txo + (tid-32);
                              nb = wb + 8; eoff = tid - 32; }
        else if (tid < 128) { hy = tyo + (tid-64);  hx = txo - 1;
                              nb = wb - 1; eoff = 128 + (tid-64); }
        else                { hy = tyo + (tid-128); hx = txo + 32;
                              nb = wb + 1; eoff = 64 + (tid-128); }
        hin = (hy >= 0 && hy < 256 && hx >= 0 && hx < 256);
    }
    const int hsy = hy - tyo + 1, hsx = hx - txo + 1;

    #define POOL_BLOCK() do { \
        __syncthreads(); \
        { int segrow_ = tid >> 2, segcol_ = tid & 3; \
          const float* rw_ = &s_pn[1 + segrow_][1 + segcol_*8]; \
          s_part[tid] = rw_[0]+rw_[1]+rw_[2]+rw_[3]+rw_[4]+rw_[5]+rw_[6]+rw_[7]; } \
        __syncthreads(); \
        if (tid < 32) { int brow_ = tid >> 2, bcol_ = tid & 3; float s_ = 0.f; \
          _Pragma("unroll") \
          for (int rr_ = 0; rr_ < 8; rr_++) s_ += s_part[(brow_*8 + rr_)*4 + bcol_]; \
          s_bs[tid] = s_; } \
        __syncthreads(); \
    } while (0)

    #define PUBLISH_E(arr, ebase) do { \
        float* eb_ = (ebase) + (size_t)wb*192; \
        if (tyb == 0) stg_ag(eb_ + tx, arr[0]); \
        if (tyb == 7) stg_ag(eb_ + 32 + tx, arr[7]); \
        if (tx == 0) { _Pragma("unroll") \
            for (int i_ = 0; i_ < 8; i_++) stg_ag(eb_ + 64 + tyb + 8*i_, arr[i_]); } \
        if (tx == 31){ _Pragma("unroll") \
            for (int i_ = 0; i_ < 8; i_++) stg_ag(eb_ + 128 + tyb + 8*i_, arr[i_]); } \
    } while (0)

    auto matvec = [&](int i) -> float {
        int yy = 1 + tyb + 8*i, xx = 1 + tx;
        float wvd = bf2f((short)(wc[i] & 0xffff));
        float whr = bf2f((short)(wc[i] >> 16));
        float wvu = bf2f((short)(wu[i] & 0xffff));
        float whl = bf2f((short)(wl[i] >> 16));
        float s = wvu*s_pn[yy-1][xx] + wvd*s_pn[yy+1][xx]
                + whl*s_pn[yy][xx-1] + whr*s_pn[yy][xx+1];
        float deg = wvu+wvd+whl+whr;
        return deg*s_pn[yy][xx] - s + c1[i]*s_bs[i*4 + (tx>>3)];
    };

    // block 3-dot reduce -> ONE packed 16B line {pa,pb,pc,seq} (edges drained first)
    auto publish_red = [&](unsigned seq, float va, float vb, float vc){
        #pragma unroll
        for (int o = 32; o > 0; o >>= 1) {
            va += __shfl_down(va, o, 64);
            vb += __shfl_down(vb, o, 64);
            vc += __shfl_down(vc, o, 64);
        }
        asm volatile("s_waitcnt vmcnt(0)" ::: "memory");  // per-wave edge-store drain
        __syncthreads();
        if ((tid & 63) == 0) { int wv = tid >> 6; s_w3[wv*3]=va; s_w3[wv*3+1]=vb; s_w3[wv*3+2]=vc; }
        __syncthreads();
        if (tid == 0) {
            f32x4 pk;
            pk[0] = s_w3[0]+s_w3[3]+s_w3[6]+s_w3[9];
            pk[1] = s_w3[1]+s_w3[4]+s_w3[7]+s_w3[10];
            pk[2] = s_w3[2]+s_w3[5]+s_w3[8]+s_w3[11];
            pk[3] = __uint_as_float(seq);
            stg4_ag(part4 + (size_t)((seq & 1)*512 + wb)*4, pk);
        }
    };

    // 2-level barrier + 3-dot grid reduction, packed lines both levels
    float o0, o1, o2;
    auto allred = [&](unsigned seq){
        float* resp = res4 + (size_t)(seq & 1)*64;      // 4 lines x 16 floats (64B apart)
        if (is_leader && tid < 64) {
            const float* pl = part4 + (size_t)(seq & 1)*2048;
            const float* p0 = pl + (size_t)(wb + 2*tid)*4;
            f32x4 a0 = ldg4_ag(p0);
            while (__float_as_uint(a0[3]) < seq) { __builtin_amdgcn_s_sleep(1); a0 = ldg4_ag(p0); }
            f32x4 a1 = ldg4_ag(p0 + 4);
            while (__float_as_uint(a1[3]) < seq) { __builtin_amdgcn_s_sleep(1); a1 = ldg4_ag(p0 + 4); }
            float pa = a0[0] + a1[0];
            float pb = a0[1] + a1[1];
            float pc = a0[2] + a1[2];
            #pragma unroll
            for (int o = 32; o > 0; o >>= 1) {
                pa += __shfl_down(pa, o, 64);
                pb += __shfl_down(pb, o, 64);
                pc += __shfl_down(pc, o, 64);
            }
            if (tid == 0) {
                f32x4 rk; rk[0] = pa; rk[1] = pb; rk[2] = pc; rk[3] = __uint_as_float(seq);
                stg4_ag(resp + (wb >> 7)*16, rk);
            }
        }
        if (tid < 4) {
            const float* rl = resp + tid*16;
            f32x4 g = ldg4_ag(rl);
            while (__float_as_uint(g[3]) < seq) { __builtin_amdgcn_s_sleep(2); g = ldg4_ag(rl); }
            *(f32x4*)&s_g[tid*4] = g;
        }
        __syncthreads();
        o0 = ((s_g[0]+s_g[4])+s_g[8])+s_g[12];
        o1 = ((s_g[1]+s_g[5])+s_g[9])+s_g[13];
        o2 = ((s_g[2]+s_g[6])+s_g[10])+s_g[14];
    };

    float xv[8], rv[8], pv[8], apv[8];
    float rh = 0.f, phh = 0.f;

    // ---------- phase 1 (seq=1): x0 = ybic, r0 = p0 = b - A x0 (halo via global reads);
    //            publish r0 edges -> ebuf1; packed flags-only barrier ----------
    #pragma unroll
    for (int i = 0; i < 8; i++) {
        xv[i] = ybn[idx[i]];
        s_pn[1 + tyb + 8*i][1 + tx] = xv[i];
    }
    if (hthr) s_pn[hsy][hsx] = hin ? ybn[hy*256 + hx] : 0.f;
    POOL_BLOCK();
    float g0t = 0.f;
    #pragma unroll
    for (int i = 0; i < 8; i++) {
        float ax = matvec(i);
        float r0 = rhs[i] - ax;
        rv[i] = r0; pv[i] = r0;
        g0t += r0*r0;
    }
    PUBLISH_E(pv, ebuf1);
    publish_red(1u, 0.f, 0.f, 0.f);   // barrier-only phase (values unused)
    allred(1u);

    // ---------- phase 2 (seq=2, k=0): halo r0 from neighbor edges; Ap0 = A p0;
    //            publish Ap0 edges -> ebuf0; reduce (g0, pAp0, ApAp0) ----------
    {
        float hv = 0.f;
        if (hthr && hin) hv = ldg_ag(ebuf1 + (size_t)nb*192 + eoff);
        if (hthr) { rh = hv; phh = hv; s_pn[hsy][hsx] = phh; }
        #pragma unroll
        for (int i = 0; i < 8; i++) s_pn[1 + tyb + 8*i][1 + tx] = pv[i];
        POOL_BLOCK();
        float pap = 0.f, apap = 0.f;
        #pragma unroll
        for (int i = 0; i < 8; i++) {
            float ap = matvec(i);
            apv[i] = ap;
            pap  += pv[i]*ap;
            apap += ap*ap;
        }
        PUBLISH_E(apv, ebuf0);
        publish_red(2u, g0t, pap, apap);
    }

    // ---------- main loop k=1..99 (phase seq = k+2; allred(k+1) -> prev scalars) ----------
    for (int k = 1; k <= 99; k++) {
        float* ebR = ((k+1) & 1) ? ebuf1 : ebuf0;   // neighbor Ap_{k-1} edges (seq k+1)
        float* ebW = ((k+2) & 1) ? ebuf1 : ebuf0;   // our Ap_k edges (seq k+2)

        allred((unsigned)(k + 1));                  // -> (g_{k-1}, pAp_{k-1}, ApAp_{k-1})
        float alpha = o0 / o1;
        float beta  = (alpha*alpha*o2 - o0) / o0;

        float hv = 0.f;
        if (hthr && hin) hv = ldg_ag(ebR + (size_t)nb*192 + eoff);

        float gsum = 0.f;
        #pragma unroll
        for (int i = 0; i < 8; i++) {
            float rN = fmaf(-alpha, apv[i], rv[i]);
            xv[i] = fmaf(alpha, pv[i], xv[i]);
            float pN = fmaf(beta, pv[i], rN);
            rv[i] = rN; pv[i] = pN;
            gsum += rN*rN;
            s_pn[1 + tyb + 8*i][1 + tx] = pN;
        }
        if (hthr) {
            rh  = fmaf(-alpha, hv, rh);
            phh = fmaf(beta, phh, rh);
            s_pn[hsy][hsx] = phh;
        }
        POOL_BLOCK();
        float pap = 0.f, apap = 0.f;
        #pragma unroll
        for (int i = 0; i < 8; i++) {
            float ap = matvec(i);
            apv[i] = ap;
            pap  += pv[i]*ap;
            apap += ap*ap;
        }
        PUBLISH_E(apv, ebW);
        publish_red((unsigned)(k + 2), gsum, pap, apap);
    }

    // ---------- tail: x += alpha_100 * p_99 ----------
    allred(101u);   // -> (g_99, pAp_99, ApAp_99)
    float alphaT = o0 / o1;
    float* xn = xout + (size_t)n*PLANE;
    #pragma unroll
    for (int i = 0; i < 8; i++) xn[idx[i]] = fmaf(alphaT, pv[i], xv[i]);

    #undef POOL_BLOCK
    #undef PUBLISH_E
}

// ---------------- host ----------------
extern "C" void kernel_launch(void* const* d_in, const int* in_sizes, int n_in,
                              void* d_out, int out_size, void* d_ws, size_t ws_size,
                              hipStream_t stream)
{
    (void)in_sizes; (void)n_in; (void)out_size; (void)ws_size;
    const float* guide = (const float*)d_in[0];
    const float* source= (const float*)d_in[1];
    const float* mask  = (const float*)d_in[2];
    const float* ybic  = (const float*)d_in[3];
    const float* gw1 = (const float*)d_in[4];  const float* gb1 = (const float*)d_in[5];
    const float* gw2 = (const float*)d_in[6];  const float* gb2 = (const float*)d_in[7];
    const float* sw1 = (const float*)d_in[8];  const float* sb1 = (const float*)d_in[9];
    const float* sw2 = (const float*)d_in[10]; const float* sb2 = (const float*)d_in[11];
    const float* vw1 = (const float*)d_in[12]; const float* vb1 = (const float*)d_in[13];
    const float* vw2 = (const float*)d_in[14]; const float* vb2 = (const float*)d_in[15];
    const float* vw3 = (const float*)d_in[16]; const float* vb3 = (const float*)d_in[17];
    const float* llam = (const float*)d_in[18];
    const float* lmu  = (const float*)d_in[19];

    float* out     = (float*)d_out;
    float* x_out   = out;                 // y_pred (16,1,256,256)
    float* var_out = out + 1048576;       // var
    float* aff_out = out + 2097152;       // aff (16,5,256,256)

    // ---- workspace layout ----
    char* ws = (char*)d_ws;
    float*    res4  = (float*)ws;                       // 2 parity x 4 x 16 floats [0,512)
    float*    part4 = (float*)(ws + 4096);              // 2 parity x 512 x 16B -> [4096, 20480)
    bf16*     wpk1  = (bf16*)(ws + 24576);              // 18 KiB each
    bf16*     wpk2  = (bf16*)(ws + 43008);
    bf16*     wpk3  = (bf16*)(ws + 61440);              // ends at 79872
    unsigned* wvh   = (unsigned*)(ws + 131072);         // [128 KiB, 128 KiB + 4 MiB)
    char*     A     = ws + 131072 + (size_t)NB*PLANE*4; // shared region
    // conv-phase mapping of A:
    bf16*  tmp1 = (bf16*)(A);                                  // 64 MiB
    bf16*  tmp2 = (bf16*)(A + (size_t)NB*32*PLANE*2);          // 64 MiB
    float* dv   = (float*)(A + (size_t)NB*32*PLANE*4);         // 4 MiB
    float* dh   = (float*)(A + (size_t)NB*32*PLANE*4 + (size_t)NB*PLANE*4);
    // CG-phase mapping of A (conv temporaries dead by then): compact edge buffers
    float* ebuf0 = (float*)A;                                  // 512*192 floats
    float* ebuf1 = (float*)(A + (size_t)512*192*4);

    dim3 cgrid(16, 16, NB);

    // zero res4 + part4 seq fields
    hipMemsetAsync(ws, 0, 20480, stream);

    // repack the three 32->32 conv weights into MFMA fragment layout
    wrepack3<<<108,256,0,stream>>>(gw2, sw2, vw2, wpk1, wpk2, wpk3);

    // feature branch g = conv(relu(conv(guide)))
    conv3x3_first<3,3,true><<<cgrid,256,0,stream>>>(guide, guide, gw1, gb1, tmp1);
    conv3x3_mfma<false><<<cgrid,256,0,stream>>>(tmp1, wpk1, gb2, tmp2);
    dvdh_cl<false><<<4096,256,0,stream>>>(tmp2, dv, dh);
    // feature branch s = conv(relu(conv(y_bicubic)))
    conv3x3_first<1,1,true><<<cgrid,256,0,stream>>>(ybic, ybic, sw1, sb1, tmp1);
    conv3x3_mfma<false><<<cgrid,256,0,stream>>>(tmp1, wpk2, sb2, tmp2);
    dvdh_cl<true><<<4096,256,0,stream>>>(tmp2, dv, dh);
    aff2_kernel<<<4096,256,0,stream>>>(dv, dh, llam, lmu, wvh, aff_out);
    // variance branch
    conv3x3_first<4,3,true><<<cgrid,256,0,stream>>>(guide, ybic, vw1, vb1, tmp1);
    conv3x3_mfma<true><<<cgrid,256,0,stream>>>(tmp1, wpk3, vb2, tmp2);
    conv3x3_last<<<4096,256,0,stream>>>(tmp2, vw3, vb3, var_out);

    // CG: ONE persistent dispatch — 512 workers, packed-line 2-level barrier
    cg_persist<<<512,256,0,stream>>>(wvh, mask, source, ybic, llam, x_out,
                                     ebuf0, ebuf1, part4, res4);
}

// Round 8
// 894.454 us; speedup vs baseline: 1.7596x; 1.0224x over previous
//
#include <hip/hip_runtime.h>
#include <hip/hip_bf16.h>

typedef __hip_bfloat16 bf16;
typedef __attribute__((ext_vector_type(8))) short short8;
typedef __attribute__((ext_vector_type(4))) float f32x4;

#define NB 16
#define PLANE (256*256)

static __device__ __forceinline__ short f2bf(float v){
    __hip_bfloat16 h = __float2bfloat16(v);
    short s; __builtin_memcpy(&s, &h, 2); return s;
}
static __device__ __forceinline__ float bf2f(short s){
    union { unsigned u; float f; } cv;
    cv.u = ((unsigned)(unsigned short)s) << 16; return cv.f;
}

// agent-scope (cross-XCD coherent, uncached) accesses — bypass per-XCD L2
static __device__ __forceinline__ void  stg_ag(float* p, float v){
    __hip_atomic_store(p, v, __ATOMIC_RELAXED, __HIP_MEMORY_SCOPE_AGENT);
}
static __device__ __forceinline__ float ldg_ag(const float* p){
    return __hip_atomic_load(p, __ATOMIC_RELAXED, __HIP_MEMORY_SCOPE_AGENT);
}
// packed 16B coherent store/load: payload (3 floats) + seq flag land/observe atomically
static __device__ __forceinline__ void stg4_ag(float* p, f32x4 v){
    asm volatile("global_store_dwordx4 %0, %1, off sc0 sc1" :: "v"(p), "v"(v) : "memory");
}
static __device__ __forceinline__ f32x4 ldg4_ag(const float* p){
    f32x4 r;
    asm volatile("global_load_dwordx4 %0, %1, off sc0 sc1\n\ts_waitcnt vmcnt(0)"
                 : "=v"(r) : "v"(p) : "memory");
    return r;
}

// ---------------- first-layer conv 3x3 (small CIN, VALU), output channel-last bf16 ----------------
template<int CIN, int SPLIT, bool RELU>
__global__ __launch_bounds__(256)
void conv3x3_first(const float* __restrict__ in, const float* __restrict__ in2,
                   const float* __restrict__ wgt, const float* __restrict__ bias,
                   bf16* __restrict__ out)
{
    __shared__ float s_in[CIN][18][18];
    __shared__ float s_w[CIN*9*32];
    const int n  = blockIdx.z;
    const int ty0 = blockIdx.y * 16, tx0 = blockIdx.x * 16;
    const int tid = threadIdx.x;

    for (int idx = tid; idx < CIN*9*32; idx += 256) {
        int co = idx & 31; int rest = idx >> 5;     // rest = ci*9 + k
        s_w[idx] = wgt[(co*CIN + rest/9)*9 + rest%9];
    }
    for (int idx = tid; idx < CIN*18*18; idx += 256) {
        int ci = idx / (18*18); int rr = idx % (18*18);
        int yy = rr / 18, xx = rr % 18;
        int y = ty0 + yy - 1, x = tx0 + xx - 1;
        float v = 0.f;
        if (y >= 0 && y < 256 && x >= 0 && x < 256) {
            if (ci < SPLIT) v = in [((size_t)(n*SPLIT + ci)*256 + y)*256 + x];
            else            v = in2[((size_t)(n*(CIN-SPLIT) + (ci-SPLIT))*256 + y)*256 + x];
        }
        s_in[ci][yy][xx] = v;
    }
    __syncthreads();

    const int ty = tid >> 4, tx = tid & 15;
    float acc[32];
    #pragma unroll
    for (int co = 0; co < 32; co++) acc[co] = bias[co];

    #pragma unroll
    for (int ci = 0; ci < CIN; ci++) {
        #pragma unroll
        for (int ky = 0; ky < 3; ky++)
        #pragma unroll
        for (int kx = 0; kx < 3; kx++) {
            float v = s_in[ci][ty+ky][tx+kx];
            const float* wp = &s_w[(ci*9 + ky*3 + kx)*32];
            #pragma unroll
            for (int co = 0; co < 32; co++) acc[co] = fmaf(v, wp[co], acc[co]);
        }
    }
    const int y = ty0 + ty, x = tx0 + tx;
    size_t base = (((size_t)n*256 + y)*256 + x)*32;
    #pragma unroll
    for (int c = 0; c < 32; c += 8) {
        short8 vv;
        #pragma unroll
        for (int j = 0; j < 8; j++) {
            float v = acc[c+j];
            if (RELU) v = fmaxf(v, 0.f);
            vv[j] = f2bf(v);
        }
        *(short8*)((short*)out + base + c) = vv;
    }
}

// ---------------- weight repack for MFMA convs: [co][ci][tap] f32 -> [tap][co][ci] bf16 ----------------
__global__ __launch_bounds__(256)
void wrepack3(const float* __restrict__ a, const float* __restrict__ b,
              const float* __restrict__ c,
              bf16* __restrict__ oa, bf16* __restrict__ ob, bf16* __restrict__ oc)
{
    int j = blockIdx.x*256 + threadIdx.x;        // 0..27647
    if (j >= 3*9216) return;
    int set = j / 9216, r = j % 9216;
    int tap = r >> 10, rem = r & 1023, co = rem >> 5, ci = rem & 31;
    const float* src = (set == 0) ? a : (set == 1) ? b : c;
    bf16* dst = (set == 0) ? oa : (set == 1) ? ob : oc;
    dst[r] = __float2bfloat16(src[(co*32 + ci)*9 + tap]);
}

// ---------------- heavy conv 3x3 (32->32) via MFMA, LDS-staged input (v branch) ----------------
template<bool RELU>
__global__ __launch_bounds__(256)
void conv3x3_mfma(const bf16* __restrict__ in, const bf16* __restrict__ wpk,
                  const float* __restrict__ bias, bf16* __restrict__ out)
{
    __shared__ __align__(16) short s_a[4*2640];
    const int tid = threadIdx.x;
    const int lane = tid & 63, wid = tid >> 6;
    const int m = lane & 15, quad = lane >> 4, k0 = quad*8;
    const int n  = blockIdx.z;
    const int x0 = blockIdx.x * 16;
    const int y0 = blockIdx.y * 16;

    const short* inp = (const short*)in + (size_t)n*PLANE*32;
    short* outp = (short*)out + (size_t)n*PLANE*32;

    for (int c = tid; c < 1296; c += 256) {
        int q = c & 3, px = c >> 2;
        int yy = px / 18, xx = px - yy*18;
        int gy = y0 + yy - 1, gx = x0 + xx - 1;
        short8 v = {0,0,0,0,0,0,0,0};
        if ((unsigned)gy < 256u && (unsigned)gx < 256u)
            v = *(const short8*)(inp + ((size_t)(gy*256 + gx))*32 + q*8);
        *(short8*)(s_a + q*2640 + (yy*18 + xx)*8) = v;
    }

    const short* wp = (const short*)wpk;
    short8 bw[2][9];
    #pragma unroll
    for (int g = 0; g < 2; g++)
        #pragma unroll
        for (int tap = 0; tap < 9; tap++)
            bw[g][tap] = *(const short8*)(wp + ((tap*32 + g*16 + m)*32 + k0));
    const float b0 = bias[m], b1 = bias[16 + m];
    __syncthreads();

    const short* sa = s_a + quad*2640;
    #pragma unroll
    for (int r = 0; r < 4; r++) {
        const int lr = wid*4 + r;
        f32x4 acc0 = { b0, b0, b0, b0 };
        f32x4 acc1 = { b1, b1, b1, b1 };
        #pragma unroll
        for (int ky = 0; ky < 3; ky++)
        #pragma unroll
        for (int kx = 0; kx < 3; kx++) {
            short8 a = *(const short8*)(sa + ((lr+ky)*18 + (m+kx))*8);
            acc0 = __builtin_amdgcn_mfma_f32_16x16x32_bf16(a, bw[0][ky*3+kx], acc0, 0, 0, 0);
            acc1 = __builtin_amdgcn_mfma_f32_16x16x32_bf16(a, bw[1][ky*3+kx], acc1, 0, 0, 0);
        }
        const int y = y0 + lr;
        #pragma unroll
        for (int reg = 0; reg < 4; reg++) {
            int px = x0 + quad*4 + reg;
            size_t idx = ((size_t)y*256 + px)*32;
            float v0 = acc0[reg], v1 = acc1[reg];
            if (RELU) { v0 = fmaxf(v0, 0.f); v1 = fmaxf(v1, 0.f); }
            outp[idx + m]      = f2bf(v0);
            outp[idx + 16 + m] = f2bf(v1);
        }
    }
}

// ======== fused conv2(MFMA) + dvdh for feature branches: no tmp2 round-trip ========
// Computes a 17x17 conv2 tile per block (row16 = one extra strip; col16 via a strip
// whose A-fragment is valid in row 0 only — D[0,:] depends only on A[0,:], so the
// pixel is BIT-IDENTICAL to the neighbor block's MFMA result). Values bf16-rounded
// into LDS (same rounding point as the old tmp2 global store), then dv/dh computed
// with dvdh_cl's exact per-pixel FMA order and written directly (8 MB instead of a
// 128 MB tmp2 round-trip).
template<bool ACCUM>
__global__ __launch_bounds__(256, 2)
void conv3x3_mfma_dvdh(const bf16* __restrict__ in, const bf16* __restrict__ wpk,
                       const float* __restrict__ bias,
                       float* __restrict__ dv, float* __restrict__ dh)
{
    __shared__ __align__(16) short s_a[4*2896];     // conv1 19x19 halo tile, 4 ch-slices
    __shared__ __align__(16) short s_f[17*17*40];   // conv2 out 17x17, 40-short px stride (pad)
    const int tid = threadIdx.x;
    const int lane = tid & 63, wid = tid >> 6;
    const int m = lane & 15, quad = lane >> 4, k0 = quad*8;
    const int n  = blockIdx.z;
    const int x0 = blockIdx.x * 16;
    const int y0 = blockIdx.y * 16;

    const short* inp = (const short*)in + (size_t)n*PLANE*32;

    // stage 19x19 halo tile of conv1 output (global), zero-padded outside image
    for (int c = tid; c < 1444; c += 256) {
        int q = c & 3, px = c >> 2;
        int yy = px / 19, xx = px - yy*19;
        int gy = y0 + yy - 1, gx = x0 + xx - 1;
        short8 v = {0,0,0,0,0,0,0,0};
        if ((unsigned)gy < 256u && (unsigned)gx < 256u)
            v = *(const short8*)(inp + ((size_t)(gy*256 + gx))*32 + q*8);
        *(short8*)(s_a + q*2896 + (yy*19 + xx)*8) = v;
    }

    const short* wp = (const short*)wpk;
    short8 bw[2][9];
    #pragma unroll
    for (int g = 0; g < 2; g++)
        #pragma unroll
        for (int tap = 0; tap < 9; tap++)
            bw[g][tap] = *(const short8*)(wp + ((tap*32 + g*16 + m)*32 + k0));
    const float b0 = bias[m], b1 = bias[16 + m];
    __syncthreads();

    const short* sa = s_a + quad*2896;

    // main strips: wave wid covers local rows {wid, wid+4, wid+8, wid+12, (wid+16)}
    for (int ru = 0; ru < 5; ru++) {
        const int yl = wid + 4*ru;                  // 0..16
        if (yl > 16) break;
        f32x4 acc0 = { b0, b0, b0, b0 };
        f32x4 acc1 = { b1, b1, b1, b1 };
        #pragma unroll
        for (int ky = 0; ky < 3; ky++)
        #pragma unroll
        for (int kx = 0; kx < 3; kx++) {
            short8 a = *(const short8*)(sa + ((yl+ky)*19 + (kx+m))*8);
            acc0 = __builtin_amdgcn_mfma_f32_16x16x32_bf16(a, bw[0][ky*3+kx], acc0, 0, 0, 0);
            acc1 = __builtin_amdgcn_mfma_f32_16x16x32_bf16(a, bw[1][ky*3+kx], acc1, 0, 0, 0);
        }
        #pragma unroll
        for (int reg = 0; reg < 4; reg++) {
            int c = quad*4 + reg;
            short* fp = s_f + (yl*17 + c)*40;
            fp[m]      = f2bf(acc0[reg]);
            fp[16 + m] = f2bf(acc1[reg]);
        }
    }

    // extra-col strip: pixel col 16, rows 0..15 (A row 0 valid; rows>0 garbage, discarded)
    for (int ru = 0; ru < 4; ru++) {
        const int yl = wid + 4*ru;                  // 0..15
        f32x4 acc0 = { b0, b0, b0, b0 };
        f32x4 acc1 = { b1, b1, b1, b1 };
        #pragma unroll
        for (int ky = 0; ky < 3; ky++)
        #pragma unroll
        for (int kx = 0; kx < 3; kx++) {
            int col = 16 + kx + m; if (col > 18) col = 18;   // m>0 lanes: clamped garbage
            short8 a = *(const short8*)(sa + ((yl+ky)*19 + col)*8);
            acc0 = __builtin_amdgcn_mfma_f32_16x16x32_bf16(a, bw[0][ky*3+kx], acc0, 0, 0, 0);
            acc1 = __builtin_amdgcn_mfma_f32_16x16x32_bf16(a, bw[1][ky*3+kx], acc1, 0, 0, 0);
        }
        if (quad == 0) {                            // D row 0 lives in quad-0 lanes
            short* fp = s_f + (yl*17 + 16)*40;
            fp[m]      = f2bf(acc0[0]);
            fp[16 + m] = f2bf(acc1[0]);
        }
    }
    __syncthreads();

    // dv/dh for the 16x16 tile — exact dvdh_cl ordering
    const int ty = tid >> 4, tx = tid & 15;
    const int i = y0 + ty, j = x0 + tx;
    const short8* pc = (const short8*)(s_f + (ty*17 + tx)*40);
    const short8* pr = (j < 255) ? (const short8*)(s_f + (ty*17 + tx + 1)*40) : pc;
    const short8* pd = (i < 255) ? (const short8*)(s_f + ((ty+1)*17 + tx)*40) : pc;
    float adv = 0.f, adh = 0.f;
    #pragma unroll
    for (int c4 = 0; c4 < 4; c4++) {
        short8 sc = pc[c4], sr = pr[c4], sd = pd[c4];
        #pragma unroll
        for (int e = 0; e < 8; e++) {
            float fc = bf2f(sc[e]);
            float d1 = bf2f(sr[e]) - fc;
            float d2 = bf2f(sd[e]) - fc;
            adh = fmaf(d1, d1, adh);
            adv = fmaf(d2, d2, adv);
        }
    }
    int o = (n*256 + i)*256 + j;
    if (ACCUM) { dv[o] += adv; dh[o] += adh; }
    else       { dv[o]  = adv; dh[o]  = adh; }
}

// ---------------- final conv 3x3 (32->1), channel-last input ----------------
__global__ __launch_bounds__(256)
void conv3x3_last(const bf16* __restrict__ in, const float* __restrict__ wgt,
                  const float* __restrict__ bias, float* __restrict__ out)
{
    __shared__ float s_w[288];
    int tid = threadIdx.x;
    for (int i = tid; i < 288; i += 256) s_w[i] = wgt[i];
    __syncthreads();
    int gid = blockIdx.x*256 + tid;
    int n = gid >> 16, h = (gid >> 8) & 255, w = gid & 255;
    const short* inp = (const short*)in + (size_t)n*PLANE*32;
    float sum = bias[0];
    #pragma unroll
    for (int ky = 0; ky < 3; ky++) {
        int yy = h + ky - 1;
        if ((unsigned)yy >= 256u) continue;
        #pragma unroll
        for (int kx = 0; kx < 3; kx++) {
            int xx = w + kx - 1;
            if ((unsigned)xx >= 256u) continue;
            const short8* pp = (const short8*)(inp + ((size_t)yy*256 + xx)*32);
            int tap = ky*3 + kx;
            #pragma unroll
            for (int c4 = 0; c4 < 4; c4++) {
                short8 v = pp[c4];
                #pragma unroll
                for (int j = 0; j < 8; j++)
                    sum = fmaf(bf2f(v[j]), s_w[(c4*8+j)*9 + tap], sum);
            }
        }
    }
    out[gid] = sum;
}

// ---------------- affinity: packed bf16 (wv,wh) for CG + 5-plane fp32 output ----------------
__global__ __launch_bounds__(256)
void aff2_kernel(const float* __restrict__ dv, const float* __restrict__ dh,
                 const float* __restrict__ llam, const float* __restrict__ lmu,
                 unsigned* __restrict__ wvh, float* __restrict__ aff)
{
    int bid = blockIdx.x;
    int n = bid >> 8, h = bid & 255, w = threadIdx.x;
    float mu = expf(lmu[0]), lam = expf(llam[0]);
    int rb = (n*256 + h)*256 + w;
    float wvv = (h < 255) ? expf(-mu * dv[rb]) : 0.f;
    float whv = (w < 255) ? expf(-mu * dh[rb]) : 0.f;
    unsigned pv = (unsigned)(unsigned short)f2bf(wvv);
    unsigned ph = (unsigned)(unsigned short)f2bf(whv);
    wvh[rb] = pv | (ph << 16);
    float w_up = (h > 0) ? expf(-mu * dv[rb - 256]) : 0.f;
    float w_lf = (w > 0) ? expf(-mu * dh[rb - 1])   : 0.f;
    float ctr  = w_up + wvv + w_lf + whv + lam;
    float* a = aff + ((size_t)n*5)*PLANE + h*256 + w;
    a[0]        = w_up;
    a[PLANE]    = wvv;
    a[2*PLANE]  = w_lf;
    a[3*PLANE]  = whv;
    a[4*PLANE]  = ctr;
}

// ============ persistent CG: 512 workers, 2-level reduce, PACKED 16B sync lines ============
__global__ __launch_bounds__(256, 2)
void cg_persist(const unsigned* __restrict__ wvh, const float* __restrict__ mask,
                const float* __restrict__ src, const float* __restrict__ ybic,
                const float* __restrict__ llam, float* __restrict__ xout,
                float* __restrict__ ebuf0, float* __restrict__ ebuf1,
                float* __restrict__ part4, float* __restrict__ res4)
{
    __shared__ float s_pn[66][34];
    __shared__ float s_part[256], s_bs[32];
    __shared__ float s_w3[12];
    __shared__ __align__(16) float s_g[16];

    const int tid = threadIdx.x;
    const int wb = blockIdx.x;
    const int n = wb >> 5, t = wb & 31;
    const int tyo = (t >> 3) * 64, txo = (t & 7) * 32;
    const int tx = tid & 31, tyb = tid >> 5;
    const int w = txo + tx;
    const float lam = expf(llam[0]);
    const bool is_leader = ((wb & 127) == 0);

    const unsigned* wn = wvh + (size_t)n*PLANE;
    const float* ybn = ybic + (size_t)n*PLANE;

    int idx[8];
    unsigned wc[8], wu[8], wl[8];
    float c1[8], rhs[8];
    #pragma unroll
    for (int i = 0; i < 8; i++) {
        int hhi = tyo + tyb + 8*i;
        idx[i] = hhi*256 + w;
        wc[i] = wn[idx[i]];
        wu[i] = (hhi > 0) ? wn[idx[i]-256] : 0u;
        wl[i] = (w > 0)   ? wn[idx[i]-1]   : 0u;
        int bi = n*1024 + (hhi>>3)*32 + (w>>3);
        float mv = mask[bi];
        c1[i]  = lam*mv*(1.f/4096.f);
        rhs[i] = lam*mv*src[bi]*(1.f/64.f);
    }

    const bool hthr = (tid < 192);
    int hy = 0, hx = 0; bool hin = false; int nb = 0, eoff = 0;
    if (hthr) {
        if      (tid < 32)  { hy = tyo - 1;         hx = txo + tid;
                              nb = wb - 8; eoff = 32 + tid; }
        else if (tid < 64)  { hy = tyo + 64;        hx = txo + (tid-32);
                              nb = wb + 8; eoff = tid - 32; }
        else if (tid < 128) { hy = tyo + (tid-64);  hx = txo - 1;
                              nb = wb - 1; eoff = 128 + (tid-64); }
        else                { hy = tyo + (tid-128); hx = txo + 32;
                              nb = wb + 1; eoff = 64 + (tid-128); }
        hin = (hy >= 0 && hy < 256 && hx >= 0 && hx < 256);
    }
    const int hsy = hy - tyo + 1, hsx = hx - txo + 1;

    #define POOL_BLOCK() do { \
        __syncthreads(); \
        { int segrow_ = tid >> 2, segcol_ = tid & 3; \
          const float* rw_ = &s_pn[1 + segrow_][1 + segcol_*8]; \
          s_part[tid] = rw_[0]+rw_[1]+rw_[2]+rw_[3]+rw_[4]+rw_[5]+rw_[6]+rw_[7]; } \
        __syncthreads(); \
        if (tid < 32) { int brow_ = tid >> 2, bcol_ = tid & 3; float s_ = 0.f; \
          _Pragma("unroll") \
          for (int rr_ = 0; rr_ < 8; rr_++) s_ += s_part[(brow_*8 + rr_)*4 + bcol_]; \
          s_bs[tid] = s_; } \
        __syncthreads(); \
    } while (0)

    #define PUBLISH_E(arr, ebase) do { \
        float* eb_ = (ebase) + (size_t)wb*192; \
        if (tyb == 0) stg_ag(eb_ + tx, arr[0]); \
        if (tyb == 7) stg_ag(eb_ + 32 + tx, arr[7]); \
        if (tx == 0) { _Pragma("unroll") \
            for (int i_ = 0; i_ < 8; i_++) stg_ag(eb_ + 64 + tyb + 8*i_, arr[i_]); } \
        if (tx == 31){ _Pragma("unroll") \
            for (int i_ = 0; i_ < 8; i_++) stg_ag(eb_ + 128 + tyb + 8*i_, arr[i_]); } \
    } while (0)

    auto matvec = [&](int i) -> float {
        int yy = 1 + tyb + 8*i, xx = 1 + tx;
        float wvd = bf2f((short)(wc[i] & 0xffff));
        float whr = bf2f((short)(wc[i] >> 16));
        float wvu = bf2f((short)(wu[i] & 0xffff));
        float whl = bf2f((short)(wl[i] >> 16));
        float s = wvu*s_pn[yy-1][xx] + wvd*s_pn[yy+1][xx]
                + whl*s_pn[yy][xx-1] + whr*s_pn[yy][xx+1];
        float deg = wvu+wvd+whl+whr;
        return deg*s_pn[yy][xx] - s + c1[i]*s_bs[i*4 + (tx>>3)];
    };

    auto publish_red = [&](unsigned seq, float va, float vb, float vc){
        #pragma unroll
        for (int o = 32; o > 0; o >>= 1) {
            va += __shfl_down(va, o, 64);
            vb += __shfl_down(vb, o, 64);
            vc += __shfl_down(vc, o, 64);
        }
        asm volatile("s_waitcnt vmcnt(0)" ::: "memory");  // per-wave edge-store drain
        __syncthreads();
        if ((tid & 63) == 0) { int wv = tid >> 6; s_w3[wv*3]=va; s_w3[wv*3+1]=vb; s_w3[wv*3+2]=vc; }
        __syncthreads();
        if (tid == 0) {
            f32x4 pk;
            pk[0] = s_w3[0]+s_w3[3]+s_w3[6]+s_w3[9];
            pk[1] = s_w3[1]+s_w3[4]+s_w3[7]+s_w3[10];
            pk[2] = s_w3[2]+s_w3[5]+s_w3[8]+s_w3[11];
            pk[3] = __uint_as_float(seq);
            stg4_ag(part4 + (size_t)((seq & 1)*512 + wb)*4, pk);
        }
    };

    float o0, o1, o2;
    auto allred = [&](unsigned seq){
        float* resp = res4 + (size_t)(seq & 1)*64;      // 4 lines x 16 floats (64B apart)
        if (is_leader && tid < 64) {
            const float* pl = part4 + (size_t)(seq & 1)*2048;
            const float* p0 = pl + (size_t)(wb + 2*tid)*4;
            f32x4 a0 = ldg4_ag(p0);
            while (__float_as_uint(a0[3]) < seq) { __builtin_amdgcn_s_sleep(1); a0 = ldg4_ag(p0); }
            f32x4 a1 = ldg4_ag(p0 + 4);
            while (__float_as_uint(a1[3]) < seq) { __builtin_amdgcn_s_sleep(1); a1 = ldg4_ag(p0 + 4); }
            float pa = a0[0] + a1[0];
            float pb = a0[1] + a1[1];
            float pc = a0[2] + a1[2];
            #pragma unroll
            for (int o = 32; o > 0; o >>= 1) {
                pa += __shfl_down(pa, o, 64);
                pb += __shfl_down(pb, o, 64);
                pc += __shfl_down(pc, o, 64);
            }
            if (tid == 0) {
                f32x4 rk; rk[0] = pa; rk[1] = pb; rk[2] = pc; rk[3] = __uint_as_float(seq);
                stg4_ag(resp + (wb >> 7)*16, rk);
            }
        }
        if (tid < 4) {
            const float* rl = resp + tid*16;
            f32x4 g = ldg4_ag(rl);
            while (__float_as_uint(g[3]) < seq) { __builtin_amdgcn_s_sleep(2); g = ldg4_ag(rl); }
            *(f32x4*)&s_g[tid*4] = g;
        }
        __syncthreads();
        o0 = ((s_g[0]+s_g[4])+s_g[8])+s_g[12];
        o1 = ((s_g[1]+s_g[5])+s_g[9])+s_g[13];
        o2 = ((s_g[2]+s_g[6])+s_g[10])+s_g[14];
    };

    float xv[8], rv[8], pv[8], apv[8];
    float rh = 0.f, phh = 0.f;

    // ---------- phase 1 (seq=1) ----------
    #pragma unroll
    for (int i = 0; i < 8; i++) {
        xv[i] = ybn[idx[i]];
        s_pn[1 + tyb + 8*i][1 + tx] = xv[i];
    }
    if (hthr) s_pn[hsy][hsx] = hin ? ybn[hy*256 + hx] : 0.f;
    POOL_BLOCK();
    float g0t = 0.f;
    #pragma unroll
    for (int i = 0; i < 8; i++) {
        float ax = matvec(i);
        float r0 = rhs[i] - ax;
        rv[i] = r0; pv[i] = r0;
        g0t += r0*r0;
    }
    PUBLISH_E(pv, ebuf1);
    publish_red(1u, 0.f, 0.f, 0.f);   // barrier-only phase
    allred(1u);

    // ---------- phase 2 (seq=2, k=0) ----------
    {
        float hv = 0.f;
        if (hthr && hin) hv = ldg_ag(ebuf1 + (size_t)nb*192 + eoff);
        if (hthr) { rh = hv; phh = hv; s_pn[hsy][hsx] = phh; }
        #pragma unroll
        for (int i = 0; i < 8; i++) s_pn[1 + tyb + 8*i][1 + tx] = pv[i];
        POOL_BLOCK();
        float pap = 0.f, apap = 0.f;
        #pragma unroll
        for (int i = 0; i < 8; i++) {
            float ap = matvec(i);
            apv[i] = ap;
            pap  += pv[i]*ap;
            apap += ap*ap;
        }
        PUBLISH_E(apv, ebuf0);
        publish_red(2u, g0t, pap, apap);
    }

    // ---------- main loop k=1..99 ----------
    for (int k = 1; k <= 99; k++) {
        float* ebR = ((k+1) & 1) ? ebuf1 : ebuf0;
        float* ebW = ((k+2) & 1) ? ebuf1 : ebuf0;

        allred((unsigned)(k + 1));
        float alpha = o0 / o1;
        float beta  = (alpha*alpha*o2 - o0) / o0;

        float hv = 0.f;
        if (hthr && hin) hv = ldg_ag(ebR + (size_t)nb*192 + eoff);

        float gsum = 0.f;
        #pragma unroll
        for (int i = 0; i < 8; i++) {
            float rN = fmaf(-alpha, apv[i], rv[i]);
            xv[i] = fmaf(alpha, pv[i], xv[i]);
            float pN = fmaf(beta, pv[i], rN);
            rv[i] = rN; pv[i] = pN;
            gsum += rN*rN;
            s_pn[1 + tyb + 8*i][1 + tx] = pN;
        }
        if (hthr) {
            rh  = fmaf(-alpha, hv, rh);
            phh = fmaf(beta, phh, rh);
            s_pn[hsy][hsx] = phh;
        }
        POOL_BLOCK();
        float pap = 0.f, apap = 0.f;
        #pragma unroll
        for (int i = 0; i < 8; i++) {
            float ap = matvec(i);
            apv[i] = ap;
            pap  += pv[i]*ap;
            apap += ap*ap;
        }
        PUBLISH_E(apv, ebW);
        publish_red((unsigned)(k + 2), gsum, pap, apap);
    }

    // ---------- tail ----------
    allred(101u);
    float alphaT = o0 / o1;
    float* xn = xout + (size_t)n*PLANE;
    #pragma unroll
    for (int i = 0; i < 8; i++) xn[idx[i]] = fmaf(alphaT, pv[i], xv[i]);

    #undef POOL_BLOCK
    #undef PUBLISH_E
}

// ---------------- host ----------------
extern "C" void kernel_launch(void* const* d_in, const int* in_sizes, int n_in,
                              void* d_out, int out_size, void* d_ws, size_t ws_size,
                              hipStream_t stream)
{
    (void)in_sizes; (void)n_in; (void)out_size; (void)ws_size;
    const float* guide = (const float*)d_in[0];
    const float* source= (const float*)d_in[1];
    const float* mask  = (const float*)d_in[2];
    const float* ybic  = (const float*)d_in[3];
    const float* gw1 = (const float*)d_in[4];  const float* gb1 = (const float*)d_in[5];
    const float* gw2 = (const float*)d_in[6];  const float* gb2 = (const float*)d_in[7];
    const float* sw1 = (const float*)d_in[8];  const float* sb1 = (const float*)d_in[9];
    const float* sw2 = (const float*)d_in[10]; const float* sb2 = (const float*)d_in[11];
    const float* vw1 = (const float*)d_in[12]; const float* vb1 = (const float*)d_in[13];
    const float* vw2 = (const float*)d_in[14]; const float* vb2 = (const float*)d_in[15];
    const float* vw3 = (const float*)d_in[16]; const float* vb3 = (const float*)d_in[17];
    const float* llam = (const float*)d_in[18];
    const float* lmu  = (const float*)d_in[19];

    float* out     = (float*)d_out;
    float* x_out   = out;                 // y_pred (16,1,256,256)
    float* var_out = out + 1048576;       // var
    float* aff_out = out + 2097152;       // aff (16,5,256,256)

    // ---- workspace layout ----
    char* ws = (char*)d_ws;
    float*    res4  = (float*)ws;                       // 2 parity x 4 x 16 floats [0,512)
    float*    part4 = (float*)(ws + 4096);              // 2 parity x 512 x 16B -> [4096, 20480)
    bf16*     wpk1  = (bf16*)(ws + 24576);              // 18 KiB each
    bf16*     wpk2  = (bf16*)(ws + 43008);
    bf16*     wpk3  = (bf16*)(ws + 61440);              // ends at 79872
    unsigned* wvh   = (unsigned*)(ws + 131072);         // [128 KiB, 128 KiB + 4 MiB)
    char*     A     = ws + 131072 + (size_t)NB*PLANE*4; // shared region
    // conv-phase mapping of A:
    bf16*  tmp1 = (bf16*)(A);                                  // 64 MiB
    bf16*  tmp2 = (bf16*)(A + (size_t)NB*32*PLANE*2);          // 64 MiB (v branch only)
    float* dv   = (float*)(A + (size_t)NB*32*PLANE*4);         // 4 MiB
    float* dh   = (float*)(A + (size_t)NB*32*PLANE*4 + (size_t)NB*PLANE*4);
    // CG-phase mapping of A (conv temporaries dead by then): compact edge buffers
    float* ebuf0 = (float*)A;                                  // 512*192 floats
    float* ebuf1 = (float*)(A + (size_t)512*192*4);

    dim3 cgrid(16, 16, NB);

    // zero res4 + part4 seq fields
    hipMemsetAsync(ws, 0, 20480, stream);

    // repack the three 32->32 conv weights into MFMA fragment layout
    wrepack3<<<108,256,0,stream>>>(gw2, sw2, vw2, wpk1, wpk2, wpk3);

    // feature branch g: conv1 -> fused conv2+dvdh (writes dv/dh directly)
    conv3x3_first<3,3,true><<<cgrid,256,0,stream>>>(guide, guide, gw1, gb1, tmp1);
    conv3x3_mfma_dvdh<false><<<cgrid,256,0,stream>>>(tmp1, wpk1, gb2, dv, dh);
    // feature branch s: conv1 -> fused conv2+dvdh (accumulate)
    conv3x3_first<1,1,true><<<cgrid,256,0,stream>>>(ybic, ybic, sw1, sb1, tmp1);
    conv3x3_mfma_dvdh<true><<<cgrid,256,0,stream>>>(tmp1, wpk2, sb2, dv, dh);
    aff2_kernel<<<4096,256,0,stream>>>(dv, dh, llam, lmu, wvh, aff_out);
    // variance branch (unchanged)
    conv3x3_first<4,3,true><<<cgrid,256,0,stream>>>(guide, ybic, vw1, vb1, tmp1);
    conv3x3_mfma<true><<<cgrid,256,0,stream>>>(tmp1, wpk3, vb2, tmp2);
    conv3x3_last<<<4096,256,0,stream>>>(tmp2, vw3, vb3, var_out);

    // CG: ONE persistent dispatch — 512 workers, packed-line 2-level barrier
    cg_persist<<<512,256,0,stream>>>(wvh, mask, source, ybic, llam, x_out,
                                     ebuf0, ebuf1, part4, res4);
}